// Round 2
// baseline (212.235 us; speedup 1.0000x reference)
//
#include <hip/hip_runtime.h>
#include <hip/hip_cooperative_groups.h>
#include <math.h>

namespace cg = cooperative_groups;

// ---------------- ws layout (float indices) ----------------
#define W_MUP    0                         // 256: per-(plane,quarter) sums
#define W_LOP    256                       // 256: per-block cos min partials
#define W_HIP    512                       // 256: per-block cos max partials
#define W_CMXP   768                       // 256: per-block co-max partials
#define W_COS    1024                      // 4*65536
#define W_GP     (W_COS + 262144)          // 256 blocks * 256: gram partials
#define W_H2     (W_GP + 65536)            // 4*128*256
#define W_RAW    (W_H2 + 131072)           // 4*128*256: o1 pre-BN
#define W_BN1P   (W_RAW + 131072)          // 128*2*2: (S,S2) per (ch,half)
#define W_BN2P   (W_BN1P + 512)            // 128*2*4: (A0,A1,S2,pad)

// ---------------- wave-64 reductions ----------------
__device__ __forceinline__ float wrSum(float v){
#pragma unroll
  for(int o = 32; o > 0; o >>= 1) v += __shfl_down(v, o, 64);
  return v;
}
__device__ __forceinline__ float wrSumX(float v){   // butterfly: all lanes get result
#pragma unroll
  for(int o = 32; o > 0; o >>= 1) v += __shfl_xor(v, o, 64);
  return v;
}
__device__ __forceinline__ float wrMax(float v){
#pragma unroll
  for(int o = 32; o > 0; o >>= 1) v = fmaxf(v, __shfl_down(v, o, 64));
  return v;
}
__device__ __forceinline__ float wrMin(float v){
#pragma unroll
  for(int o = 32; o > 0; o >>= 1) v = fminf(v, __shfl_down(v, o, 64));
  return v;
}

__global__ __launch_bounds__(256)
void k_mega(const float* __restrict__ x,
            const float* __restrict__ f1w, const float* __restrict__ f1b,
            const float* __restrict__ f2w, const float* __restrict__ f2b,
            const float* __restrict__ o1w, const float* __restrict__ o1b,
            const float* __restrict__ g1,  const float* __restrict__ b1,
            const float* __restrict__ o2w, const float* __restrict__ o2b,
            const float* __restrict__ g2,  const float* __restrict__ b2,
            float* __restrict__ ws, float* __restrict__ out)
{
  cg::grid_group gridg = cg::this_grid();
  __shared__ float smem[10496];            // 41 KB, re-carved per phase
  const int t = threadIdx.x;
  const int b = blockIdx.x;

  // ================= P0: mu partials (x pass 1) =================
  {
    const int plane = b >> 2, q = b & 3;
    const float4* xp = (const float4*)(x + plane*65536 + q*16384);
    float s = 0.0f;
#pragma unroll
    for(int k = 0; k < 16; ++k){ float4 v = xp[t + k*256]; s += (v.x+v.y)+(v.z+v.w); }
    s = wrSum(s);
    if((t & 63) == 0) smem[t >> 6] = s;
    __syncthreads();
    if(t == 0) ws[W_MUP + b] = (smem[0]+smem[1])+(smem[2]+smem[3]);
  }
  gridg.sync();

  // ================= P1: cos field (x pass 2) + min/max partials =================
  {
    const int n = b >> 6, rg = b & 63;
    if(t < 64) smem[t] = ws[W_MUP + n*64 + t];
    __syncthreads();
    if(t < 16) smem[64 + t] = (smem[4*t]+smem[4*t+1]+smem[4*t+2]+smem[4*t+3]) * (1.0f/65536.0f);
    __syncthreads();
    float mn[16], nn = 0.0f;
#pragma unroll
    for(int c = 0; c < 16; ++c){ mn[c] = smem[64 + c]; nn += mn[c]*mn[c]; }
    const float inv = 1.0f / fmaxf(sqrtf(nn), 1e-12f);
    float lo = 1e30f, hi = -1e30f;
#pragma unroll
    for(int k = 0; k < 4; ++k){
      const int p = (rg*4 + k)*256 + t;
      const float* xp = x + n*1048576 + p;
      float dot = 0.0f, xx = 0.0f;
#pragma unroll
      for(int c = 0; c < 16; ++c){ float v = xp[c*65536]; dot += v*mn[c]; xx += v*v; }
      float cv = dot * inv / fmaxf(sqrtf(xx), 1e-12f);
      ws[W_COS + n*65536 + p] = cv;
      lo = fminf(lo, cv); hi = fmaxf(hi, cv);
    }
    __syncthreads();
    lo = wrMin(lo); hi = wrMax(hi);
    if((t & 63) == 0){ smem[t >> 6] = lo; smem[4 + (t >> 6)] = hi; }
    __syncthreads();
    if(t == 0){
      ws[W_LOP + b] = fminf(fminf(smem[0],smem[1]),fminf(smem[2],smem[3]));
      ws[W_HIP + b] = fmaxf(fmaxf(smem[4],smem[5]),fmaxf(smem[6],smem[7]));
    }
  }
  gridg.sync();

  // ================= P2: quant + Gram partials + co-max partials =================
  {
    float* Lsh = smem;            // 5120
    float* Rsh = smem + 5120;     // 5120
    const int n = b >> 6, h0 = (b & 63) << 2;
    if(t < 64){
      float lo = ws[W_LOP + n*64 + t];
      float hi = ws[W_HIP + n*64 + t];
      lo = wrMin(lo); hi = wrMax(hi);
      if(t == 0){ smem[10240] = lo; smem[10241] = hi; }
    }
    __syncthreads();
    const float cmin = smem[10240];
    const float dqv  = smem[10241] - cmin;
    float q[16];
#pragma unroll
    for(int l = 0; l < 16; ++l) q[l] = (float)(2*l+1) * (1.0f/32.0f) * dqv + cmin;

    const int m  = t & 15;
    const int g  = t >> 4;
    const int i0 = (m >> 2) << 2;
    const int j0 = (m & 3) << 2;
    float acc[4][4] = {{0.0f}};
    float mp = 0.0f;
    const float* cosp = ws + W_COS + n*65536;

    __syncthreads();
    for(int ch = 0; ch < 4; ++ch){
      const int h = h0 + ch;
      const float cl = cosp[h*256 + t];
      const bool valid = (h < 255) && (t < 255);
      const float cr = valid ? cosp[h*256 + t + 257] : 0.0f;
      float lv[16], rv[16];
      float mL = 0.0f, mR = 0.0f;
#pragma unroll
      for(int l = 0; l < 16; ++l){
        float dl = cl - q[l];
        float Lv = __expf(-32.0f * dl * dl);
        float dr = cr - q[l];
        float Rv = valid ? __expf(-32.0f * dr * dr) : 0.0f;
        lv[l] = Lv; rv[l] = Rv;
        mL = fmaxf(mL, Lv); mR = fmaxf(mR, Rv);
      }
      mp = fmaxf(mp, mL * mR);
      float4* Lp = (float4*)&Lsh[t * 20];
      float4* Rp = (float4*)&Rsh[t * 20];
#pragma unroll
      for(int k = 0; k < 4; ++k){
        Lp[k] = make_float4(lv[4*k], lv[4*k+1], lv[4*k+2], lv[4*k+3]);
        Rp[k] = make_float4(rv[4*k], rv[4*k+1], rv[4*k+2], rv[4*k+3]);
      }
      __syncthreads();
#pragma unroll 4
      for(int it = 0; it < 16; ++it){
        const int p = it * 16 + g;
        const float4 Lx = *(const float4*)&Lsh[p*20 + i0];
        const float4 Rx = *(const float4*)&Rsh[p*20 + j0];
        const float lf[4] = {Lx.x, Lx.y, Lx.z, Lx.w};
        const float rf[4] = {Rx.x, Rx.y, Rx.z, Rx.w};
#pragma unroll
        for(int a = 0; a < 4; ++a)
#pragma unroll
          for(int bb = 0; bb < 4; ++bb) acc[a][bb] += lf[a] * rf[bb];
      }
      __syncthreads();
    }
#pragma unroll
    for(int a = 0; a < 4; ++a)
#pragma unroll
      for(int bb = 0; bb < 4; ++bb)
        Lsh[t*16 + a*4 + bb] = acc[a][bb];
    __syncthreads();
    const int i = t >> 4, j = t & 15;
    const int mm = ((i >> 2) << 2) + (j >> 2);
    const int idx = mm*16 + (i & 3)*4 + (j & 3);
    float v = 0.0f;
#pragma unroll
    for(int gg = 0; gg < 16; ++gg) v += Lsh[gg*256 + idx];
    ws[W_GP + b*256 + t] = v;

    mp = wrMax(mp);
    if((t & 63) == 0) smem[10244 + (t >> 6)] = mp;
    __syncthreads();
    if(t == 0)
      ws[W_CMXP + b] = fmaxf(fmaxf(smem[10244],smem[10245]),fmaxf(smem[10246],smem[10247]));
  }
  gridg.sync();

  // ================= P3: sta + f1(leaky) + f2(relu) -> h2 =================
  {
    // f2w transposed [c][ch] stride 129: smem[0..8255]
    for(int k = 0; k < 32; ++k){
      int idx = k*256 + t;
      smem[(idx & 63)*129 + (idx >> 6)] = f2w[idx];
    }
    if(t < 192) smem[8256 + t] = f1w[t];
    if(t < 64)  smem[8448 + t] = f1b[t];
    {
      float m = ws[W_CMXP + t];
      m = wrMax(m);
      if((t & 63) == 0) smem[9536 + (t >> 6)] = m;
    }
    const int n = b >> 6, pos0 = (b & 63) << 2;
    if(t < 64){
      float lo = ws[W_LOP + n*64 + t];
      float hi = ws[W_HIP + n*64 + t];
      lo = wrMin(lo); hi = wrMax(hi);
      if(t == 0){ smem[9540] = lo; smem[9541] = hi; }
    }
    __syncthreads();
    const float comax = fmaxf(fmaxf(smem[9536],smem[9537]),fmaxf(smem[9538],smem[9539]));
    const float cmin = smem[9540];
    const float dqv  = smem[9541] - cmin;
    const int w = t >> 6, j = t & 63;
    const int pos = pos0 + w;
    float gv = ws[W_GP + (n*64 + j)*256 + pos];
    gv = wrSumX(gv);
    const float sta = gv / (comax + 1e-6f);
    const int l1 = pos >> 4, l2 = pos & 15;
    const float ft0 = (float)(2*l2+1)*(1.0f/32.0f)*dqv + cmin;
    const float ft1 = (float)(2*l1+1)*(1.0f/32.0f)*dqv + cmin;
    float a = smem[8256+3*j]*ft0 + smem[8256+3*j+1]*ft1 + smem[8256+3*j+2]*sta + smem[8448+j];
    smem[8512 + w*64 + j] = (a > 0.0f) ? a : 0.01f*a;
    __syncthreads();
    float acc0 = f2b[j], acc1 = f2b[j+64];
    const float* h1p = &smem[8512 + w*64];
#pragma unroll
    for(int c = 0; c < 64; ++c){
      float hv = h1p[c];
      acc0 += smem[c*129 + j]      * hv;
      acc1 += smem[c*129 + j + 64] * hv;
    }
    acc0 = fmaxf(acc0, 0.0f); acc1 = fmaxf(acc1, 0.0f);
    smem[8768 + j*6 + w]        = acc0;     // h2buf[ch][w], stride 6
    smem[8768 + (j+64)*6 + w]   = acc1;
    __syncthreads();
    {
      const int ch = t >> 1, hf = t & 1;
      float v0 = smem[8768 + ch*6 + hf*2];
      float v1 = smem[8768 + ch*6 + hf*2 + 1];
      float* dst = ws + W_H2 + n*32768 + ch*256 + pos0 + hf*2;
      dst[0] = v0; dst[1] = v1;
    }
  }
  gridg.sync();

  // ================= P4: o1 conv (raw) + BN1 stats partials =================
  {
    const int ch = b >> 1, hf = b & 1;
    const int n0 = hf * 2;
    if(t < 144) smem[t] = o1w[ch*144 + t];
    if(t >= 192 && t < 224){
      int i = t - 192;               // (n-local)*16 + c
      int nn = n0 + (i >> 4), c = i & 15;
      int base = (nn*16 + c)*4;
      smem[144 + i] = (ws[W_MUP+base]+ws[W_MUP+base+1]+ws[W_MUP+base+2]+ws[W_MUP+base+3])*(1.0f/65536.0f);
    }
    __syncthreads();
    float acc0 = o1b[ch], acc1 = acc0;
#pragma unroll
    for(int c = 0; c < 16; ++c){
      float wv = smem[c];
      acc0 += wv * smem[144 + c];
      acc1 += wv * smem[160 + c];
    }
    const float* h2p = ws + W_H2 + n0*32768 + t;
    for(int c = 0; c < 128; ++c){
      float wv = smem[16 + c];
      acc0 += wv * h2p[c*256];
      acc1 += wv * h2p[32768 + c*256];
    }
    ws[W_RAW + n0*32768     + ch*256 + t] = acc0;
    ws[W_RAW + (n0+1)*32768 + ch*256 + t] = acc1;
    float s = acc0 + acc1, s2 = acc0*acc0 + acc1*acc1;
    s = wrSum(s); s2 = wrSum(s2);
    if((t & 63) == 0){ smem[176 + (t>>6)] = s; smem[180 + (t>>6)] = s2; }
    __syncthreads();
    if(t == 0){
      ws[W_BN1P + (ch*2 + hf)*2]     = smem[176]+smem[177]+smem[178]+smem[179];
      ws[W_BN1P + (ch*2 + hf)*2 + 1] = smem[180]+smem[181]+smem[182]+smem[183];
    }
  }
  gridg.sync();

  // ================= P5: BN1+relu (inline) + o2 conv + BN2 partials =================
  {
    const int ch = b >> 1, hf = b & 1, n0 = hf*2;
    if(t < 128){
      float S  = ws[W_BN1P + (t*2+0)*2]     + ws[W_BN1P + (t*2+1)*2];
      float S2 = ws[W_BN1P + (t*2+0)*2 + 1] + ws[W_BN1P + (t*2+1)*2 + 1];
      float mean = S * (1.0f/1024.0f);
      float var  = S2 * (1.0f/1024.0f) - mean*mean;
      float sc = g1[t] * rsqrtf(var + 1e-5f);
      smem[t]       = sc;
      smem[128 + t] = b1[t] - mean*sc;
      smem[256 + t] = o2w[ch*128 + t];
    }
    __syncthreads();
    float acc0 = o2b[ch], acc1 = acc0;
    const float* rp = ws + W_RAW + n0*32768 + t;
    for(int c = 0; c < 128; ++c){
      float sc = smem[c], sh = smem[128 + c], wv = smem[256 + c];
      float h0v = fmaxf(rp[c*256]*sc + sh, 0.0f);
      float h1v = fmaxf(rp[32768 + c*256]*sc + sh, 0.0f);
      acc0 += wv * h0v; acc1 += wv * h1v;
    }
    float s2 = acc0*acc0 + acc1*acc1;
    float r0 = wrSum(acc0), r1 = wrSum(acc1), r2 = wrSum(s2);
    if((t & 63) == 0){ int w = t>>6; smem[384+w] = r0; smem[388+w] = r1; smem[392+w] = r2; }
    __syncthreads();
    if(t == 0){
      float A0 = smem[384]+smem[385]+smem[386]+smem[387];
      float A1 = smem[388]+smem[389]+smem[390]+smem[391];
      float S2 = smem[392]+smem[393]+smem[394]+smem[395];
      float* dst = ws + W_BN2P + (ch*2 + hf)*4;
      dst[0] = A0; dst[1] = A1; dst[2] = S2;
    }
  }
  gridg.sync();

  // ================= P6: BN2 finalize + threshold/redistribute/normalize =================
  if(b == 0){
    if(t < 128){
      const float* p0 = ws + W_BN2P + (t*2)*4;
      const float* p1 = ws + W_BN2P + (t*2+1)*4;
      float A[4] = {p0[0], p0[1], p1[0], p1[1]};
      float S2 = p0[2] + p1[2];
      float S  = A[0]+A[1]+A[2]+A[3];
      float mean = S * (1.0f/1024.0f);
      float var  = S2 * (1.0f/1024.0f) - mean*mean;
      float sc = g2[t] * rsqrtf(var + 1e-5f);
      float sh = b2[t] - mean*sc;
#pragma unroll
      for(int n = 0; n < 4; ++n) smem[n*128 + t] = A[n]*(1.0f/256.0f)*sc + sh;
    }
    __syncthreads();
    float v0 = smem[t], v1 = smem[256 + t];
    float m = fmaxf(v0, v1);
    m = wrMax(m);
    if((t & 63) == 0) smem[512 + (t>>6)] = m;
    __syncthreads();
    const float mx = fmaxf(fmaxf(smem[512],smem[513]),fmaxf(smem[514],smem[515]));
    const float thr = 0.5f * mx;      // THETA = 0.5
    float e = fmaxf(v0 - thr, 0.0f) + fmaxf(v1 - thr, 0.0f);
    e = wrSum(e);
    if((t & 63) == 0) smem[516 + (t>>6)] = e;
    __syncthreads();
    const float r = (smem[516]+smem[517]+smem[518]+smem[519]) * (1.0f/16.0f);
    const float d0 = (v0 > thr) ? (thr + r) : (v0 + r);
    const float d1 = (v1 > thr) ? (thr + r) : (v1 + r);
    float dn = fminf(d0, d1), dx = fmaxf(d0, d1);
    dn = wrMin(dn); dx = wrMax(dx);
    if((t & 63) == 0){ smem[520 + (t>>6)] = dn; smem[524 + (t>>6)] = dx; }
    __syncthreads();
    const float DN = fminf(fminf(smem[520],smem[521]),fminf(smem[522],smem[523]));
    const float DX = fmaxf(fmaxf(smem[524],smem[525]),fmaxf(smem[526],smem[527]));
    const float inv = 1.0f / (DX - DN + 1e-6f);
    out[t]       = (d0 - DN) * inv;
    out[256 + t] = (d1 - DN) * inv;
  }
}

extern "C" void kernel_launch(void* const* d_in, const int* in_sizes, int n_in,
                              void* d_out, int out_size, void* d_ws, size_t ws_size,
                              hipStream_t stream){
  (void)in_sizes; (void)n_in; (void)out_size; (void)ws_size;
  const float* x   = (const float*)d_in[0];
  const float* f1w = (const float*)d_in[1];
  const float* f1b = (const float*)d_in[2];
  const float* f2w = (const float*)d_in[3];
  const float* f2b = (const float*)d_in[4];
  const float* o1w = (const float*)d_in[5];
  const float* o1b = (const float*)d_in[6];
  const float* g1  = (const float*)d_in[7];
  const float* b1  = (const float*)d_in[8];
  const float* o2w = (const float*)d_in[9];
  const float* o2b = (const float*)d_in[10];
  const float* g2  = (const float*)d_in[11];
  const float* b2  = (const float*)d_in[12];
  float* ws  = (float*)d_ws;
  float* out = (float*)d_out;

  void* kargs[] = {
    (void*)&x, (void*)&f1w, (void*)&f1b, (void*)&f2w, (void*)&f2b,
    (void*)&o1w, (void*)&o1b, (void*)&g1, (void*)&b1,
    (void*)&o2w, (void*)&o2b, (void*)&g2, (void*)&b2,
    (void*)&ws, (void*)&out
  };
  hipLaunchCooperativeKernel((void*)k_mega, dim3(256), dim3(256), kargs, 0, stream);
}

// Round 3
// 198.232 us; speedup vs baseline: 1.0706x; 1.0706x over previous
//
#include <hip/hip_runtime.h>
#include <math.h>

#define NBLK 256

// ---------------- ws layout (float indices) ----------------
#define W_MUP    0                         // 256 blocks * 16ch: pixel-block channel sums
#define W_LOP    4096                      // 256: per-block cos min partials
#define W_HIP    4352                      // 256: per-block cos max partials
#define W_CMXP   4608                      // 256: per-block co-max partials
#define W_BAR    4864                      // 16 barriers x 32 uints (spaced cachelines)
#define W_COS    8192                      // 4*65536
#define W_GP     (W_COS + 262144)          // 256 blocks * 256: gram partials
#define W_H2     (W_GP + 65536)            // 4*128*256
#define W_RAW    (W_H2 + 131072)           // 4*128*256: o1 pre-BN
#define W_BN1P   (W_RAW + 131072)          // 128*2*2: (S,S2) per (ch,half)
#define W_BN2P   (W_BN1P + 512)            // 128*2*4: (A0,A1,S2,pad)

// ---------------- wave-64 reductions ----------------
__device__ __forceinline__ float wrSum(float v){
#pragma unroll
  for(int o = 32; o > 0; o >>= 1) v += __shfl_down(v, o, 64);
  return v;
}
__device__ __forceinline__ float wrSumX(float v){
#pragma unroll
  for(int o = 32; o > 0; o >>= 1) v += __shfl_xor(v, o, 64);
  return v;
}
__device__ __forceinline__ float wrMax(float v){
#pragma unroll
  for(int o = 32; o > 0; o >>= 1) v = fmaxf(v, __shfl_down(v, o, 64));
  return v;
}
__device__ __forceinline__ float wrMin(float v){
#pragma unroll
  for(int o = 32; o > 0; o >>= 1) v = fminf(v, __shfl_down(v, o, 64));
  return v;
}

// ---------------- fast device-scope grid barrier ----------------
__device__ __forceinline__ void gbar(unsigned* bars, int idx){
  __syncthreads();
  if(threadIdx.x == 0){
    __threadfence();                                   // release prior global writes (cross-XCD)
    unsigned* c = bars + idx*32;
    __hip_atomic_fetch_add(c, 1u, __ATOMIC_ACQ_REL, __HIP_MEMORY_SCOPE_AGENT);
    while(__hip_atomic_load(c, __ATOMIC_ACQUIRE, __HIP_MEMORY_SCOPE_AGENT) < (unsigned)NBLK){
      __builtin_amdgcn_s_sleep(2);
    }
    __threadfence();                                   // acquire: invalidate stale cached lines
  }
  __syncthreads();
}

// ---------------- K0: zero barrier counters ----------------
__global__ __launch_bounds__(512) void k_zero(float* __restrict__ ws){
  unsigned* u = (unsigned*)ws;
  if(threadIdx.x < 512) u[W_BAR + threadIdx.x] = 0u;
}

__global__ __launch_bounds__(256)
void k_mega(const float* __restrict__ x,
            const float* __restrict__ f1w, const float* __restrict__ f1b,
            const float* __restrict__ f2w, const float* __restrict__ f2b,
            const float* __restrict__ o1w, const float* __restrict__ o1b,
            const float* __restrict__ g1,  const float* __restrict__ b1,
            const float* __restrict__ o2w, const float* __restrict__ o2b,
            const float* __restrict__ g2,  const float* __restrict__ b2,
            float* __restrict__ ws, float* __restrict__ out)
{
  __shared__ __align__(16) float smem[10496];          // 41 KB, re-carved per phase
  const int t = threadIdx.x;
  const int b = blockIdx.x;
  unsigned* bars = (unsigned*)ws + W_BAR;

  // ================= P0: per-(block,channel) sums, pixel-blocked (x pass 1) =================
  {
    const int n = b >> 6, pg = b & 63;                 // 1024 pixels per block
    const float* xb = x + n*1048576 + pg*1024;
    float s[16];
#pragma unroll
    for(int c = 0; c < 16; ++c){
      float4 v = *(const float4*)(xb + c*65536 + t*4);
      s[c] = (v.x+v.y)+(v.z+v.w);
    }
#pragma unroll
    for(int c = 0; c < 16; ++c){
      float r = wrSum(s[c]);
      if((t & 63) == 0) smem[c*4 + (t>>6)] = r;
    }
    __syncthreads();
    if(t < 16) ws[W_MUP + b*16 + t] = (smem[t*4]+smem[t*4+1])+(smem[t*4+2]+smem[t*4+3]);
  }
  gbar(bars, 0);

  // ================= P1: cos field (x pass 2, L2-local) + min/max partials =================
  {
    const int n = b >> 6, rg = b & 63;
    ((float4*)smem)[t] = ((const float4*)(ws + W_MUP + n*1024))[t];   // 1024 partials
    __syncthreads();
    if(t < 16){
      float s = 0.0f;
#pragma unroll
      for(int pg = 0; pg < 64; ++pg) s += smem[pg*16 + t];
      smem[1024 + t] = s * (1.0f/65536.0f);
    }
    __syncthreads();
    float mn[16], nn = 0.0f;
#pragma unroll
    for(int c = 0; c < 16; ++c){ mn[c] = smem[1024 + c]; nn += mn[c]*mn[c]; }
    const float inv = 1.0f / fmaxf(sqrtf(nn), 1e-12f);
    float lo = 1e30f, hi = -1e30f;
#pragma unroll
    for(int k = 0; k < 4; ++k){
      const int p = (rg*4 + k)*256 + t;
      const float* xp = x + n*1048576 + p;
      float dot = 0.0f, xx = 0.0f;
#pragma unroll
      for(int c = 0; c < 16; ++c){ float v = xp[c*65536]; dot += v*mn[c]; xx += v*v; }
      float cv = dot * inv / fmaxf(sqrtf(xx), 1e-12f);
      ws[W_COS + n*65536 + p] = cv;
      lo = fminf(lo, cv); hi = fmaxf(hi, cv);
    }
    __syncthreads();
    lo = wrMin(lo); hi = wrMax(hi);
    if((t & 63) == 0){ smem[t >> 6] = lo; smem[4 + (t >> 6)] = hi; }
    __syncthreads();
    if(t == 0){
      ws[W_LOP + b] = fminf(fminf(smem[0],smem[1]),fminf(smem[2],smem[3]));
      ws[W_HIP + b] = fmaxf(fmaxf(smem[4],smem[5]),fmaxf(smem[6],smem[7]));
    }
  }
  gbar(bars, 1);

  // ================= P2: quant + Gram partials + co-max partials =================
  {
    float* Lsh = smem;            // 5120
    float* Rsh = smem + 5120;     // 5120
    const int n = b >> 6, h0 = (b & 63) << 2;
    if(t < 64){
      float lo = ws[W_LOP + n*64 + t];
      float hi = ws[W_HIP + n*64 + t];
      lo = wrMin(lo); hi = wrMax(hi);
      if(t == 0){ smem[10240] = lo; smem[10241] = hi; }
    }
    __syncthreads();
    const float cmin = smem[10240];
    const float dqv  = smem[10241] - cmin;
    float q[16];
#pragma unroll
    for(int l = 0; l < 16; ++l) q[l] = (float)(2*l+1) * (1.0f/32.0f) * dqv + cmin;

    const int m  = t & 15;
    const int g  = t >> 4;
    const int i0 = (m >> 2) << 2;
    const int j0 = (m & 3) << 2;
    float acc[4][4] = {{0.0f}};
    float mp = 0.0f;
    const float* cosp = ws + W_COS + n*65536;

    __syncthreads();
    for(int ch = 0; ch < 4; ++ch){
      const int h = h0 + ch;
      const float cl = cosp[h*256 + t];
      const bool valid = (h < 255) && (t < 255);
      const float cr = valid ? cosp[h*256 + t + 257] : 0.0f;
      float lv[16], rv[16];
      float mL = 0.0f, mR = 0.0f;
#pragma unroll
      for(int l = 0; l < 16; ++l){
        float dl = cl - q[l];
        float Lv = __expf(-32.0f * dl * dl);
        float dr = cr - q[l];
        float Rv = valid ? __expf(-32.0f * dr * dr) : 0.0f;
        lv[l] = Lv; rv[l] = Rv;
        mL = fmaxf(mL, Lv); mR = fmaxf(mR, Rv);
      }
      mp = fmaxf(mp, mL * mR);
      float4* Lp = (float4*)&Lsh[t * 20];
      float4* Rp = (float4*)&Rsh[t * 20];
#pragma unroll
      for(int k = 0; k < 4; ++k){
        Lp[k] = make_float4(lv[4*k], lv[4*k+1], lv[4*k+2], lv[4*k+3]);
        Rp[k] = make_float4(rv[4*k], rv[4*k+1], rv[4*k+2], rv[4*k+3]);
      }
      __syncthreads();
#pragma unroll 4
      for(int it = 0; it < 16; ++it){
        const int p = it * 16 + g;
        const float4 Lx = *(const float4*)&Lsh[p*20 + i0];
        const float4 Rx = *(const float4*)&Rsh[p*20 + j0];
        const float lf[4] = {Lx.x, Lx.y, Lx.z, Lx.w};
        const float rf[4] = {Rx.x, Rx.y, Rx.z, Rx.w};
#pragma unroll
        for(int a = 0; a < 4; ++a)
#pragma unroll
          for(int bb = 0; bb < 4; ++bb) acc[a][bb] += lf[a] * rf[bb];
      }
      __syncthreads();
    }
#pragma unroll
    for(int a = 0; a < 4; ++a)
#pragma unroll
      for(int bb = 0; bb < 4; ++bb)
        Lsh[t*16 + a*4 + bb] = acc[a][bb];
    __syncthreads();
    const int i = t >> 4, j = t & 15;
    const int mm = ((i >> 2) << 2) + (j >> 2);
    const int idx = mm*16 + (i & 3)*4 + (j & 3);
    float v = 0.0f;
#pragma unroll
    for(int gg = 0; gg < 16; ++gg) v += Lsh[gg*256 + idx];
    ws[W_GP + b*256 + t] = v;

    mp = wrMax(mp);
    if((t & 63) == 0) smem[10244 + (t >> 6)] = mp;
    __syncthreads();
    if(t == 0)
      ws[W_CMXP + b] = fmaxf(fmaxf(smem[10244],smem[10245]),fmaxf(smem[10246],smem[10247]));
  }
  gbar(bars, 2);

  // ================= P3: sta + f1(leaky) + f2(relu) -> h2 =================
  {
    for(int k = 0; k < 32; ++k){
      int idx = k*256 + t;
      smem[(idx & 63)*129 + (idx >> 6)] = f2w[idx];    // f2w^T, stride 129
    }
    if(t < 192) smem[8256 + t] = f1w[t];
    if(t < 64)  smem[8448 + t] = f1b[t];
    {
      float m = ws[W_CMXP + t];
      m = wrMax(m);
      if((t & 63) == 0) smem[9536 + (t >> 6)] = m;
    }
    const int n = b >> 6, pos0 = (b & 63) << 2;
    if(t < 64){
      float lo = ws[W_LOP + n*64 + t];
      float hi = ws[W_HIP + n*64 + t];
      lo = wrMin(lo); hi = wrMax(hi);
      if(t == 0){ smem[9540] = lo; smem[9541] = hi; }
    }
    __syncthreads();
    const float comax = fmaxf(fmaxf(smem[9536],smem[9537]),fmaxf(smem[9538],smem[9539]));
    const float cmin = smem[9540];
    const float dqv  = smem[9541] - cmin;
    const int w = t >> 6, j = t & 63;
    const int pos = pos0 + w;
    float gv = ws[W_GP + (n*64 + j)*256 + pos];
    gv = wrSumX(gv);
    const float sta = gv / (comax + 1e-6f);
    const int l1 = pos >> 4, l2 = pos & 15;
    const float ft0 = (float)(2*l2+1)*(1.0f/32.0f)*dqv + cmin;
    const float ft1 = (float)(2*l1+1)*(1.0f/32.0f)*dqv + cmin;
    float a = smem[8256+3*j]*ft0 + smem[8256+3*j+1]*ft1 + smem[8256+3*j+2]*sta + smem[8448+j];
    smem[8512 + w*64 + j] = (a > 0.0f) ? a : 0.01f*a;
    __syncthreads();
    float acc0 = f2b[j], acc1 = f2b[j+64];
    const float* h1p = &smem[8512 + w*64];
#pragma unroll
    for(int c = 0; c < 64; ++c){
      float hv = h1p[c];
      acc0 += smem[c*129 + j]      * hv;
      acc1 += smem[c*129 + j + 64] * hv;
    }
    acc0 = fmaxf(acc0, 0.0f); acc1 = fmaxf(acc1, 0.0f);
    smem[8768 + j*6 + w]        = acc0;
    smem[8768 + (j+64)*6 + w]   = acc1;
    __syncthreads();
    {
      const int ch = t >> 1, hf = t & 1;
      float v0 = smem[8768 + ch*6 + hf*2];
      float v1 = smem[8768 + ch*6 + hf*2 + 1];
      float* dst = ws + W_H2 + n*32768 + ch*256 + pos0 + hf*2;
      dst[0] = v0; dst[1] = v1;
    }
  }
  gbar(bars, 3);

  // ================= P4: o1 conv (raw) + BN1 stats partials =================
  {
    const int ch = b >> 1, hf = b & 1;
    const int n0 = hf * 2;
    if(t < 144) smem[t] = o1w[ch*144 + t];
    if(t >= 192 && t < 224){
      int i = t - 192;               // (n-local)*16 + c
      int nn = n0 + (i >> 4), c = i & 15;
      float s = 0.0f;
      const float* mp = ws + W_MUP + nn*1024 + c;
#pragma unroll 8
      for(int pg = 0; pg < 64; ++pg) s += mp[pg*16];
      smem[144 + i] = s * (1.0f/65536.0f);
    }
    __syncthreads();
    float acc0 = o1b[ch], acc1 = acc0;
#pragma unroll
    for(int c = 0; c < 16; ++c){
      float wv = smem[c];
      acc0 += wv * smem[144 + c];
      acc1 += wv * smem[160 + c];
    }
    const float* h2p = ws + W_H2 + n0*32768 + t;
    for(int c = 0; c < 128; ++c){
      float wv = smem[16 + c];
      acc0 += wv * h2p[c*256];
      acc1 += wv * h2p[32768 + c*256];
    }
    ws[W_RAW + n0*32768     + ch*256 + t] = acc0;
    ws[W_RAW + (n0+1)*32768 + ch*256 + t] = acc1;
    float s = acc0 + acc1, s2 = acc0*acc0 + acc1*acc1;
    s = wrSum(s); s2 = wrSum(s2);
    if((t & 63) == 0){ smem[176 + (t>>6)] = s; smem[180 + (t>>6)] = s2; }
    __syncthreads();
    if(t == 0){
      ws[W_BN1P + (ch*2 + hf)*2]     = smem[176]+smem[177]+smem[178]+smem[179];
      ws[W_BN1P + (ch*2 + hf)*2 + 1] = smem[180]+smem[181]+smem[182]+smem[183];
    }
  }
  gbar(bars, 4);

  // ================= P5: BN1+relu (inline) + o2 conv + BN2 partials =================
  {
    const int ch = b >> 1, hf = b & 1, n0 = hf*2;
    if(t < 128){
      float S  = ws[W_BN1P + (t*2+0)*2]     + ws[W_BN1P + (t*2+1)*2];
      float S2 = ws[W_BN1P + (t*2+0)*2 + 1] + ws[W_BN1P + (t*2+1)*2 + 1];
      float mean = S * (1.0f/1024.0f);
      float var  = S2 * (1.0f/1024.0f) - mean*mean;
      float sc = g1[t] * rsqrtf(var + 1e-5f);
      smem[t]       = sc;
      smem[128 + t] = b1[t] - mean*sc;
      smem[256 + t] = o2w[ch*128 + t];
    }
    __syncthreads();
    float acc0 = o2b[ch], acc1 = acc0;
    const float* rp = ws + W_RAW + n0*32768 + t;
    for(int c = 0; c < 128; ++c){
      float sc = smem[c], sh = smem[128 + c], wv = smem[256 + c];
      float h0v = fmaxf(rp[c*256]*sc + sh, 0.0f);
      float h1v = fmaxf(rp[32768 + c*256]*sc + sh, 0.0f);
      acc0 += wv * h0v; acc1 += wv * h1v;
    }
    float s2 = acc0*acc0 + acc1*acc1;
    float r0 = wrSum(acc0), r1 = wrSum(acc1), r2 = wrSum(s2);
    if((t & 63) == 0){ int w = t>>6; smem[384+w] = r0; smem[388+w] = r1; smem[392+w] = r2; }
    __syncthreads();
    if(t == 0){
      float A0 = smem[384]+smem[385]+smem[386]+smem[387];
      float A1 = smem[388]+smem[389]+smem[390]+smem[391];
      float S2 = smem[392]+smem[393]+smem[394]+smem[395];
      float* dst = ws + W_BN2P + (ch*2 + hf)*4;
      dst[0] = A0; dst[1] = A1; dst[2] = S2;
    }
  }
  gbar(bars, 5);

  // ================= P6: BN2 finalize + threshold/redistribute/normalize =================
  if(b == 0){
    if(t < 128){
      const float* p0 = ws + W_BN2P + (t*2)*4;
      const float* p1 = ws + W_BN2P + (t*2+1)*4;
      float A[4] = {p0[0], p0[1], p1[0], p1[1]};
      float S2 = p0[2] + p1[2];
      float S  = A[0]+A[1]+A[2]+A[3];
      float mean = S * (1.0f/1024.0f);
      float var  = S2 * (1.0f/1024.0f) - mean*mean;
      float sc = g2[t] * rsqrtf(var + 1e-5f);
      float sh = b2[t] - mean*sc;
#pragma unroll
      for(int n = 0; n < 4; ++n) smem[n*128 + t] = A[n]*(1.0f/256.0f)*sc + sh;
    }
    __syncthreads();
    float v0 = smem[t], v1 = smem[256 + t];
    float m = fmaxf(v0, v1);
    m = wrMax(m);
    if((t & 63) == 0) smem[512 + (t>>6)] = m;
    __syncthreads();
    const float mx = fmaxf(fmaxf(smem[512],smem[513]),fmaxf(smem[514],smem[515]));
    const float thr = 0.5f * mx;      // THETA = 0.5
    float e = fmaxf(v0 - thr, 0.0f) + fmaxf(v1 - thr, 0.0f);
    e = wrSum(e);
    if((t & 63) == 0) smem[516 + (t>>6)] = e;
    __syncthreads();
    const float r = (smem[516]+smem[517]+smem[518]+smem[519]) * (1.0f/16.0f);
    const float d0 = (v0 > thr) ? (thr + r) : (v0 + r);
    const float d1 = (v1 > thr) ? (thr + r) : (v1 + r);
    float dn = fminf(d0, d1), dx = fmaxf(d0, d1);
    dn = wrMin(dn); dx = wrMax(dx);
    if((t & 63) == 0){ smem[520 + (t>>6)] = dn; smem[524 + (t>>6)] = dx; }
    __syncthreads();
    const float DN = fminf(fminf(smem[520],smem[521]),fminf(smem[522],smem[523]));
    const float DX = fmaxf(fmaxf(smem[524],smem[525]),fmaxf(smem[526],smem[527]));
    const float inv = 1.0f / (DX - DN + 1e-6f);
    out[t]       = (d0 - DN) * inv;
    out[256 + t] = (d1 - DN) * inv;
  }
}

extern "C" void kernel_launch(void* const* d_in, const int* in_sizes, int n_in,
                              void* d_out, int out_size, void* d_ws, size_t ws_size,
                              hipStream_t stream){
  (void)in_sizes; (void)n_in; (void)out_size; (void)ws_size;
  const float* x   = (const float*)d_in[0];
  const float* f1w = (const float*)d_in[1];
  const float* f1b = (const float*)d_in[2];
  const float* f2w = (const float*)d_in[3];
  const float* f2b = (const float*)d_in[4];
  const float* o1w = (const float*)d_in[5];
  const float* o1b = (const float*)d_in[6];
  const float* g1  = (const float*)d_in[7];
  const float* b1  = (const float*)d_in[8];
  const float* o2w = (const float*)d_in[9];
  const float* o2b = (const float*)d_in[10];
  const float* g2  = (const float*)d_in[11];
  const float* b2  = (const float*)d_in[12];
  float* ws  = (float*)d_ws;
  float* out = (float*)d_out;

  k_zero<<<1, 512, 0, stream>>>(ws);

  void* kargs[] = {
    (void*)&x, (void*)&f1w, (void*)&f1b, (void*)&f2w, (void*)&f2b,
    (void*)&o1w, (void*)&o1b, (void*)&g1, (void*)&b1,
    (void*)&o2w, (void*)&o2b, (void*)&g2, (void*)&b2,
    (void*)&ws, (void*)&out
  };
  hipLaunchCooperativeKernel((void*)k_mega, dim3(NBLK), dim3(256), kargs, 0, stream);
}

// Round 4
// 159.446 us; speedup vs baseline: 1.3311x; 1.2433x over previous
//
#include <hip/hip_runtime.h>
#include <math.h>

#define NBLK 256

// ---------------- ws layout (float indices) ----------------
#define W_MUP    0                         // 256 blocks * 16ch: pixel-block channel sums
#define W_LOP    4096                      // 256: per-block cos min partials
#define W_HIP    4352                      // 256: per-block cos max partials
#define W_CMXP   4608                      // 256: per-block co-max partials
#define W_BAR    4864                      // 16 barriers x 32 uints (spaced cachelines)
#define W_COS    8192                      // 4*65536
#define W_GP     (W_COS + 262144)          // 256 blocks * 256: gram partials
#define W_H2     (W_GP + 65536)            // 4*128*256
#define W_RAW    (W_H2 + 131072)           // 4*128*256: o1 pre-BN
#define W_BN1P   (W_RAW + 131072)          // 128*2*2: (S,S2) per (ch,half)
#define W_BN2P   (W_BN1P + 512)            // 128*2*4: (A0,A1,S2,pad)

// ---------------- wave-64 reductions ----------------
__device__ __forceinline__ float wrSum(float v){
#pragma unroll
  for(int o = 32; o > 0; o >>= 1) v += __shfl_down(v, o, 64);
  return v;
}
__device__ __forceinline__ float wrSumX(float v){
#pragma unroll
  for(int o = 32; o > 0; o >>= 1) v += __shfl_xor(v, o, 64);
  return v;
}
__device__ __forceinline__ float wrMax(float v){
#pragma unroll
  for(int o = 32; o > 0; o >>= 1) v = fmaxf(v, __shfl_down(v, o, 64));
  return v;
}
__device__ __forceinline__ float wrMin(float v){
#pragma unroll
  for(int o = 32; o > 0; o >>= 1) v = fminf(v, __shfl_down(v, o, 64));
  return v;
}

// ---------------- fast device-scope grid barrier ----------------
// Release: one RMW (carries wbl2). Spin: RELAXED loads (sc1 read from
// coherent point, NO buffer_inv per iteration). Acquire: single acquire
// load after the count is reached (one buffer_inv per wave).
__device__ __forceinline__ void gbar(unsigned* bars, int idx){
  __syncthreads();
  unsigned* c = bars + idx*32;
  if(threadIdx.x == 0){
    __hip_atomic_fetch_add(c, 1u, __ATOMIC_RELEASE, __HIP_MEMORY_SCOPE_AGENT);
    while(__hip_atomic_load(c, __ATOMIC_RELAXED, __HIP_MEMORY_SCOPE_AGENT) < (unsigned)NBLK){
      __builtin_amdgcn_s_sleep(4);
    }
  }
  __syncthreads();
  (void)__hip_atomic_load(c, __ATOMIC_ACQUIRE, __HIP_MEMORY_SCOPE_AGENT);
}

// ---------------- K0: zero barrier counters ----------------
__global__ __launch_bounds__(512) void k_zero(float* __restrict__ ws){
  unsigned* u = (unsigned*)ws;
  if(threadIdx.x < 512) u[W_BAR + threadIdx.x] = 0u;
}

__global__ __launch_bounds__(256)
void k_mega(const float* __restrict__ x,
            const float* __restrict__ f1w, const float* __restrict__ f1b,
            const float* __restrict__ f2w, const float* __restrict__ f2b,
            const float* __restrict__ o1w, const float* __restrict__ o1b,
            const float* __restrict__ g1,  const float* __restrict__ b1,
            const float* __restrict__ o2w, const float* __restrict__ o2b,
            const float* __restrict__ g2,  const float* __restrict__ b2,
            float* __restrict__ ws, float* __restrict__ out)
{
  __shared__ __align__(16) float smem[10496];          // 41 KB, re-carved per phase
  const int t = threadIdx.x;
  const int b = blockIdx.x;
  unsigned* bars = (unsigned*)ws + W_BAR;

  // ================= P0: per-(block,channel) sums, pixel-blocked (x pass 1) =================
  {
    const int n = b >> 6, pg = b & 63;                 // 1024 pixels per block
    const float* xb = x + n*1048576 + pg*1024;
    float s[16];
#pragma unroll
    for(int c = 0; c < 16; ++c){
      float4 v = *(const float4*)(xb + c*65536 + t*4);
      s[c] = (v.x+v.y)+(v.z+v.w);
    }
#pragma unroll
    for(int c = 0; c < 16; ++c){
      float r = wrSum(s[c]);
      if((t & 63) == 0) smem[c*4 + (t>>6)] = r;
    }
    __syncthreads();
    if(t < 16) ws[W_MUP + b*16 + t] = (smem[t*4]+smem[t*4+1])+(smem[t*4+2]+smem[t*4+3]);
  }
  gbar(bars, 0);

  // ================= P1: cos field (x pass 2, L2-local) + min/max partials =================
  {
    const int n = b >> 6, rg = b & 63;
    ((float4*)smem)[t] = ((const float4*)(ws + W_MUP + n*1024))[t];   // 1024 partials
    __syncthreads();
    if(t < 16){
      float s = 0.0f;
#pragma unroll
      for(int pg = 0; pg < 64; ++pg) s += smem[pg*16 + t];
      smem[1024 + t] = s * (1.0f/65536.0f);
    }
    __syncthreads();
    float mn[16], nn = 0.0f;
#pragma unroll
    for(int c = 0; c < 16; ++c){ mn[c] = smem[1024 + c]; nn += mn[c]*mn[c]; }
    const float inv = 1.0f / fmaxf(sqrtf(nn), 1e-12f);
    float lo = 1e30f, hi = -1e30f;
#pragma unroll
    for(int k = 0; k < 4; ++k){
      const int p = (rg*4 + k)*256 + t;
      const float* xp = x + n*1048576 + p;
      float dot = 0.0f, xx = 0.0f;
#pragma unroll
      for(int c = 0; c < 16; ++c){ float v = xp[c*65536]; dot += v*mn[c]; xx += v*v; }
      float cv = dot * inv / fmaxf(sqrtf(xx), 1e-12f);
      ws[W_COS + n*65536 + p] = cv;
      lo = fminf(lo, cv); hi = fmaxf(hi, cv);
    }
    __syncthreads();
    lo = wrMin(lo); hi = wrMax(hi);
    if((t & 63) == 0){ smem[t >> 6] = lo; smem[4 + (t >> 6)] = hi; }
    __syncthreads();
    if(t == 0){
      ws[W_LOP + b] = fminf(fminf(smem[0],smem[1]),fminf(smem[2],smem[3]));
      ws[W_HIP + b] = fmaxf(fmaxf(smem[4],smem[5]),fmaxf(smem[6],smem[7]));
    }
  }
  gbar(bars, 1);

  // ================= P2: quant + Gram partials + co-max partials =================
  {
    float* Lsh = smem;            // 5120
    float* Rsh = smem + 5120;     // 5120
    const int n = b >> 6, h0 = (b & 63) << 2;
    if(t < 64){
      float lo = ws[W_LOP + n*64 + t];
      float hi = ws[W_HIP + n*64 + t];
      lo = wrMin(lo); hi = wrMax(hi);
      if(t == 0){ smem[10240] = lo; smem[10241] = hi; }
    }
    __syncthreads();
    const float cmin = smem[10240];
    const float dqv  = smem[10241] - cmin;
    float q[16];
#pragma unroll
    for(int l = 0; l < 16; ++l) q[l] = (float)(2*l+1) * (1.0f/32.0f) * dqv + cmin;

    const int m  = t & 15;
    const int g  = t >> 4;
    const int i0 = (m >> 2) << 2;
    const int j0 = (m & 3) << 2;
    float acc[4][4] = {{0.0f}};
    float mp = 0.0f;
    const float* cosp = ws + W_COS + n*65536;

    __syncthreads();
    for(int ch = 0; ch < 4; ++ch){
      const int h = h0 + ch;
      const float cl = cosp[h*256 + t];
      const bool valid = (h < 255) && (t < 255);
      const float cr = valid ? cosp[h*256 + t + 257] : 0.0f;
      float lv[16], rv[16];
      float mL = 0.0f, mR = 0.0f;
#pragma unroll
      for(int l = 0; l < 16; ++l){
        float dl = cl - q[l];
        float Lv = __expf(-32.0f * dl * dl);
        float dr = cr - q[l];
        float Rv = valid ? __expf(-32.0f * dr * dr) : 0.0f;
        lv[l] = Lv; rv[l] = Rv;
        mL = fmaxf(mL, Lv); mR = fmaxf(mR, Rv);
      }
      mp = fmaxf(mp, mL * mR);
      float4* Lp = (float4*)&Lsh[t * 20];
      float4* Rp = (float4*)&Rsh[t * 20];
#pragma unroll
      for(int k = 0; k < 4; ++k){
        Lp[k] = make_float4(lv[4*k], lv[4*k+1], lv[4*k+2], lv[4*k+3]);
        Rp[k] = make_float4(rv[4*k], rv[4*k+1], rv[4*k+2], rv[4*k+3]);
      }
      __syncthreads();
#pragma unroll 4
      for(int it = 0; it < 16; ++it){
        const int p = it * 16 + g;
        const float4 Lx = *(const float4*)&Lsh[p*20 + i0];
        const float4 Rx = *(const float4*)&Rsh[p*20 + j0];
        const float lf[4] = {Lx.x, Lx.y, Lx.z, Lx.w};
        const float rf[4] = {Rx.x, Rx.y, Rx.z, Rx.w};
#pragma unroll
        for(int a = 0; a < 4; ++a)
#pragma unroll
          for(int bb = 0; bb < 4; ++bb) acc[a][bb] += lf[a] * rf[bb];
      }
      __syncthreads();
    }
#pragma unroll
    for(int a = 0; a < 4; ++a)
#pragma unroll
      for(int bb = 0; bb < 4; ++bb)
        Lsh[t*16 + a*4 + bb] = acc[a][bb];
    __syncthreads();
    const int i = t >> 4, j = t & 15;
    const int mm = ((i >> 2) << 2) + (j >> 2);
    const int idx = mm*16 + (i & 3)*4 + (j & 3);
    float v = 0.0f;
#pragma unroll
    for(int gg = 0; gg < 16; ++gg) v += Lsh[gg*256 + idx];
    ws[W_GP + b*256 + t] = v;

    mp = wrMax(mp);
    if((t & 63) == 0) smem[10244 + (t >> 6)] = mp;
    __syncthreads();
    if(t == 0)
      ws[W_CMXP + b] = fmaxf(fmaxf(smem[10244],smem[10245]),fmaxf(smem[10246],smem[10247]));
  }
  gbar(bars, 2);

  // ================= P3: sta + f1(leaky) + f2(relu) -> h2 =================
  {
    for(int k = 0; k < 32; ++k){
      int idx = k*256 + t;
      smem[(idx & 63)*129 + (idx >> 6)] = f2w[idx];    // f2w^T, stride 129
    }
    if(t < 192) smem[8256 + t] = f1w[t];
    if(t < 64)  smem[8448 + t] = f1b[t];
    {
      float m = ws[W_CMXP + t];
      m = wrMax(m);
      if((t & 63) == 0) smem[9536 + (t >> 6)] = m;
    }
    const int n = b >> 6, pos0 = (b & 63) << 2;
    if(t < 64){
      float lo = ws[W_LOP + n*64 + t];
      float hi = ws[W_HIP + n*64 + t];
      lo = wrMin(lo); hi = wrMax(hi);
      if(t == 0){ smem[9540] = lo; smem[9541] = hi; }
    }
    __syncthreads();
    const float comax = fmaxf(fmaxf(smem[9536],smem[9537]),fmaxf(smem[9538],smem[9539]));
    const float cmin = smem[9540];
    const float dqv  = smem[9541] - cmin;
    const int w = t >> 6, j = t & 63;
    const int pos = pos0 + w;
    float gv = ws[W_GP + (n*64 + j)*256 + pos];
    gv = wrSumX(gv);
    const float sta = gv / (comax + 1e-6f);
    const int l1 = pos >> 4, l2 = pos & 15;
    const float ft0 = (float)(2*l2+1)*(1.0f/32.0f)*dqv + cmin;
    const float ft1 = (float)(2*l1+1)*(1.0f/32.0f)*dqv + cmin;
    float a = smem[8256+3*j]*ft0 + smem[8256+3*j+1]*ft1 + smem[8256+3*j+2]*sta + smem[8448+j];
    smem[8512 + w*64 + j] = (a > 0.0f) ? a : 0.01f*a;
    __syncthreads();
    float acc0 = f2b[j], acc1 = f2b[j+64];
    const float* h1p = &smem[8512 + w*64];
#pragma unroll
    for(int c = 0; c < 64; ++c){
      float hv = h1p[c];
      acc0 += smem[c*129 + j]      * hv;
      acc1 += smem[c*129 + j + 64] * hv;
    }
    acc0 = fmaxf(acc0, 0.0f); acc1 = fmaxf(acc1, 0.0f);
    smem[8768 + j*6 + w]        = acc0;
    smem[8768 + (j+64)*6 + w]   = acc1;
    __syncthreads();
    {
      const int ch = t >> 1, hf = t & 1;
      float v0 = smem[8768 + ch*6 + hf*2];
      float v1 = smem[8768 + ch*6 + hf*2 + 1];
      float* dst = ws + W_H2 + n*32768 + ch*256 + pos0 + hf*2;
      dst[0] = v0; dst[1] = v1;
    }
  }
  gbar(bars, 3);

  // ================= P4: o1 conv (raw) + BN1 stats partials =================
  {
    const int ch = b >> 1, hf = b & 1;
    const int n0 = hf * 2;
    if(t < 144) smem[t] = o1w[ch*144 + t];
    if(t >= 192 && t < 224){
      int i = t - 192;               // (n-local)*16 + c
      int nn = n0 + (i >> 4), c = i & 15;
      float s = 0.0f;
      const float* mp = ws + W_MUP + nn*1024 + c;
#pragma unroll 8
      for(int pg = 0; pg < 64; ++pg) s += mp[pg*16];
      smem[144 + i] = s * (1.0f/65536.0f);
    }
    __syncthreads();
    float acc0 = o1b[ch], acc1 = acc0;
#pragma unroll
    for(int c = 0; c < 16; ++c){
      float wv = smem[c];
      acc0 += wv * smem[144 + c];
      acc1 += wv * smem[160 + c];
    }
    const float* h2p = ws + W_H2 + n0*32768 + t;
    for(int c = 0; c < 128; ++c){
      float wv = smem[16 + c];
      acc0 += wv * h2p[c*256];
      acc1 += wv * h2p[32768 + c*256];
    }
    ws[W_RAW + n0*32768     + ch*256 + t] = acc0;
    ws[W_RAW + (n0+1)*32768 + ch*256 + t] = acc1;
    float s = acc0 + acc1, s2 = acc0*acc0 + acc1*acc1;
    s = wrSum(s); s2 = wrSum(s2);
    if((t & 63) == 0){ smem[176 + (t>>6)] = s; smem[180 + (t>>6)] = s2; }
    __syncthreads();
    if(t == 0){
      ws[W_BN1P + (ch*2 + hf)*2]     = smem[176]+smem[177]+smem[178]+smem[179];
      ws[W_BN1P + (ch*2 + hf)*2 + 1] = smem[180]+smem[181]+smem[182]+smem[183];
    }
  }
  gbar(bars, 4);

  // ================= P5: BN1+relu (inline) + o2 conv + BN2 partials =================
  {
    const int ch = b >> 1, hf = b & 1, n0 = hf*2;
    if(t < 128){
      float S  = ws[W_BN1P + (t*2+0)*2]     + ws[W_BN1P + (t*2+1)*2];
      float S2 = ws[W_BN1P + (t*2+0)*2 + 1] + ws[W_BN1P + (t*2+1)*2 + 1];
      float mean = S * (1.0f/1024.0f);
      float var  = S2 * (1.0f/1024.0f) - mean*mean;
      float sc = g1[t] * rsqrtf(var + 1e-5f);
      smem[t]       = sc;
      smem[128 + t] = b1[t] - mean*sc;
      smem[256 + t] = o2w[ch*128 + t];
    }
    __syncthreads();
    float acc0 = o2b[ch], acc1 = acc0;
    const float* rp = ws + W_RAW + n0*32768 + t;
    for(int c = 0; c < 128; ++c){
      float sc = smem[c], sh = smem[128 + c], wv = smem[256 + c];
      float h0v = fmaxf(rp[c*256]*sc + sh, 0.0f);
      float h1v = fmaxf(rp[32768 + c*256]*sc + sh, 0.0f);
      acc0 += wv * h0v; acc1 += wv * h1v;
    }
    float s2 = acc0*acc0 + acc1*acc1;
    float r0 = wrSum(acc0), r1 = wrSum(acc1), r2 = wrSum(s2);
    if((t & 63) == 0){ int w = t>>6; smem[384+w] = r0; smem[388+w] = r1; smem[392+w] = r2; }
    __syncthreads();
    if(t == 0){
      float A0 = smem[384]+smem[385]+smem[386]+smem[387];
      float A1 = smem[388]+smem[389]+smem[390]+smem[391];
      float S2 = smem[392]+smem[393]+smem[394]+smem[395];
      float* dst = ws + W_BN2P + (ch*2 + hf)*4;
      dst[0] = A0; dst[1] = A1; dst[2] = S2;
    }
  }
  gbar(bars, 5);

  // ================= P6: BN2 finalize + threshold/redistribute/normalize =================
  if(b == 0){
    if(t < 128){
      const float* p0 = ws + W_BN2P + (t*2)*4;
      const float* p1 = ws + W_BN2P + (t*2+1)*4;
      float A[4] = {p0[0], p0[1], p1[0], p1[1]};
      float S2 = p0[2] + p1[2];
      float S  = A[0]+A[1]+A[2]+A[3];
      float mean = S * (1.0f/1024.0f);
      float var  = S2 * (1.0f/1024.0f) - mean*mean;
      float sc = g2[t] * rsqrtf(var + 1e-5f);
      float sh = b2[t] - mean*sc;
#pragma unroll
      for(int n = 0; n < 4; ++n) smem[n*128 + t] = A[n]*(1.0f/256.0f)*sc + sh;
    }
    __syncthreads();
    float v0 = smem[t], v1 = smem[256 + t];
    float m = fmaxf(v0, v1);
    m = wrMax(m);
    if((t & 63) == 0) smem[512 + (t>>6)] = m;
    __syncthreads();
    const float mx = fmaxf(fmaxf(smem[512],smem[513]),fmaxf(smem[514],smem[515]));
    const float thr = 0.5f * mx;      // THETA = 0.5
    float e = fmaxf(v0 - thr, 0.0f) + fmaxf(v1 - thr, 0.0f);
    e = wrSum(e);
    if((t & 63) == 0) smem[516 + (t>>6)] = e;
    __syncthreads();
    const float r = (smem[516]+smem[517]+smem[518]+smem[519]) * (1.0f/16.0f);
    const float d0 = (v0 > thr) ? (thr + r) : (v0 + r);
    const float d1 = (v1 > thr) ? (thr + r) : (v1 + r);
    float dn = fminf(d0, d1), dx = fmaxf(d0, d1);
    dn = wrMin(dn); dx = wrMax(dx);
    if((t & 63) == 0){ smem[520 + (t>>6)] = dn; smem[524 + (t>>6)] = dx; }
    __syncthreads();
    const float DN = fminf(fminf(smem[520],smem[521]),fminf(smem[522],smem[523]));
    const float DX = fmaxf(fmaxf(smem[524],smem[525]),fmaxf(smem[526],smem[527]));
    const float inv = 1.0f / (DX - DN + 1e-6f);
    out[t]       = (d0 - DN) * inv;
    out[256 + t] = (d1 - DN) * inv;
  }
}

extern "C" void kernel_launch(void* const* d_in, const int* in_sizes, int n_in,
                              void* d_out, int out_size, void* d_ws, size_t ws_size,
                              hipStream_t stream){
  (void)in_sizes; (void)n_in; (void)out_size; (void)ws_size;
  const float* x   = (const float*)d_in[0];
  const float* f1w = (const float*)d_in[1];
  const float* f1b = (const float*)d_in[2];
  const float* f2w = (const float*)d_in[3];
  const float* f2b = (const float*)d_in[4];
  const float* o1w = (const float*)d_in[5];
  const float* o1b = (const float*)d_in[6];
  const float* g1  = (const float*)d_in[7];
  const float* b1  = (const float*)d_in[8];
  const float* o2w = (const float*)d_in[9];
  const float* o2b = (const float*)d_in[10];
  const float* g2  = (const float*)d_in[11];
  const float* b2  = (const float*)d_in[12];
  float* ws  = (float*)d_ws;
  float* out = (float*)d_out;

  k_zero<<<1, 512, 0, stream>>>(ws);

  void* kargs[] = {
    (void*)&x, (void*)&f1w, (void*)&f1b, (void*)&f2w, (void*)&f2b,
    (void*)&o1w, (void*)&o1b, (void*)&g1, (void*)&b1,
    (void*)&o2w, (void*)&o2b, (void*)&g2, (void*)&b2,
    (void*)&ws, (void*)&out
  };
  hipLaunchCooperativeKernel((void*)k_mega, dim3(NBLK), dim3(256), kargs, 0, stream);
}

// Round 5
// 120.822 us; speedup vs baseline: 1.7566x; 1.3197x over previous
//
#include <hip/hip_runtime.h>
#include <math.h>

#define NBLK 256

// ---------------- ws layout (float indices) ----------------
#define W_MUP    0                         // 256 blocks * 16ch: pixel-block channel sums
#define W_LOP    4096                      // 256: per-block cos min partials
#define W_HIP    4352                      // 256: per-block cos max partials
#define W_CMXP   4608                      // 256: per-block co-max partials
#define W_BAR    4864                      // 6 barriers x 544 uints (16 grp lines + root)
#define W_COS    8192                      // 4*65536
#define W_GP     (W_COS + 262144)          // 256 blocks * 256: gram partials
#define W_H2     (W_GP + 65536)            // 4*128*256
#define W_RAW    (W_H2 + 131072)           // 4*128*256: o1 pre-BN
#define W_BN1P   (W_RAW + 131072)          // 128*2*2: (S,S2) per (ch,half)
#define W_BN2P   (W_BN1P + 512)            // 128*2*4: (A0,A1,S2,pad)

// ---------------- wave-64 reductions ----------------
__device__ __forceinline__ float wrSum(float v){
#pragma unroll
  for(int o = 32; o > 0; o >>= 1) v += __shfl_down(v, o, 64);
  return v;
}
__device__ __forceinline__ float wrSumX(float v){
#pragma unroll
  for(int o = 32; o > 0; o >>= 1) v += __shfl_xor(v, o, 64);
  return v;
}
__device__ __forceinline__ float wrMax(float v){
#pragma unroll
  for(int o = 32; o > 0; o >>= 1) v = fmaxf(v, __shfl_down(v, o, 64));
  return v;
}
__device__ __forceinline__ float wrMin(float v){
#pragma unroll
  for(int o = 32; o > 0; o >>= 1) v = fminf(v, __shfl_down(v, o, 64));
  return v;
}

// ---------------- fast device-scope grid barrier (2-level tree) ----------------
// Arrival: RELEASE add to per-group line (16 blocks/line, 16 lines in parallel)
// Leaders: relaxed-spin group==16, then ACQ_REL add to root (16 serialized).
// All: relaxed-spin root==16, ONE acquire load (thread 0) -> one buffer_inv
// per block, execution-ordered before the closing __syncthreads.
__device__ __forceinline__ void gbar(unsigned* bars, int idx){
  __syncthreads();
  if(threadIdx.x == 0){
    unsigned* base = bars + idx*544;
    unsigned* g    = base + ((blockIdx.x >> 4) << 5);   // 128B-spaced group lines
    unsigned* root = base + 512;
    __hip_atomic_fetch_add(g, 1u, __ATOMIC_RELEASE, __HIP_MEMORY_SCOPE_AGENT);
    if((blockIdx.x & 15) == 0){
      while(__hip_atomic_load(g, __ATOMIC_RELAXED, __HIP_MEMORY_SCOPE_AGENT) < 16u)
        __builtin_amdgcn_s_sleep(1);
      __hip_atomic_fetch_add(root, 1u, __ATOMIC_ACQ_REL, __HIP_MEMORY_SCOPE_AGENT);
    }
    while(__hip_atomic_load(root, __ATOMIC_RELAXED, __HIP_MEMORY_SCOPE_AGENT) < 16u)
      __builtin_amdgcn_s_sleep(1);
    (void)__hip_atomic_load(root, __ATOMIC_ACQUIRE, __HIP_MEMORY_SCOPE_AGENT);
  }
  __syncthreads();
}

// ---------------- K0: zero barrier counters ----------------
__global__ __launch_bounds__(512) void k_zero(float* __restrict__ ws){
  unsigned* u = (unsigned*)ws;
#pragma unroll
  for(int k = 0; k < 7; ++k){
    int i = k*512 + threadIdx.x;
    if(i < 6*544) u[W_BAR + i] = 0u;
  }
}

__global__ __launch_bounds__(256)
void k_mega(const float* __restrict__ x,
            const float* __restrict__ f1w, const float* __restrict__ f1b,
            const float* __restrict__ f2w, const float* __restrict__ f2b,
            const float* __restrict__ o1w, const float* __restrict__ o1b,
            const float* __restrict__ g1,  const float* __restrict__ b1,
            const float* __restrict__ o2w, const float* __restrict__ o2b,
            const float* __restrict__ g2,  const float* __restrict__ b2,
            float* __restrict__ ws, float* __restrict__ out)
{
  __shared__ __align__(16) float smem[10496];          // 41 KB, re-carved per phase
  const int t = threadIdx.x;
  const int b = blockIdx.x;
  unsigned* bars = (unsigned*)ws + W_BAR;

  // ================= P0: per-(block,channel) sums, pixel-blocked (x pass 1) =================
  {
    const int n = b >> 6, pg = b & 63;                 // 1024 pixels per block
    const float* xb = x + n*1048576 + pg*1024;
    float s[16];
#pragma unroll
    for(int c = 0; c < 16; ++c){
      float4 v = *(const float4*)(xb + c*65536 + t*4);
      s[c] = (v.x+v.y)+(v.z+v.w);
    }
#pragma unroll
    for(int c = 0; c < 16; ++c){
      float r = wrSum(s[c]);
      if((t & 63) == 0) smem[c*4 + (t>>6)] = r;
    }
    __syncthreads();
    if(t < 16) ws[W_MUP + b*16 + t] = (smem[t*4]+smem[t*4+1])+(smem[t*4+2]+smem[t*4+3]);
  }
  gbar(bars, 0);

  // ================= P1: cos field (x pass 2, L2-local) + min/max partials =================
  {
    const int n = b >> 6, rg = b & 63;
    ((float4*)smem)[t] = ((const float4*)(ws + W_MUP + n*1024))[t];   // 1024 partials
    __syncthreads();
    if(t < 16){
      float s = 0.0f;
#pragma unroll
      for(int pg = 0; pg < 64; ++pg) s += smem[pg*16 + t];
      smem[1024 + t] = s * (1.0f/65536.0f);
    }
    __syncthreads();
    float mn[16], nn = 0.0f;
#pragma unroll
    for(int c = 0; c < 16; ++c){ mn[c] = smem[1024 + c]; nn += mn[c]*mn[c]; }
    const float inv = 1.0f / fmaxf(sqrtf(nn), 1e-12f);
    float lo = 1e30f, hi = -1e30f;
#pragma unroll
    for(int k = 0; k < 4; ++k){
      const int p = (rg*4 + k)*256 + t;
      const float* xp = x + n*1048576 + p;
      float dot = 0.0f, xx = 0.0f;
#pragma unroll
      for(int c = 0; c < 16; ++c){ float v = xp[c*65536]; dot += v*mn[c]; xx += v*v; }
      float cv = dot * inv / fmaxf(sqrtf(xx), 1e-12f);
      ws[W_COS + n*65536 + p] = cv;
      lo = fminf(lo, cv); hi = fmaxf(hi, cv);
    }
    __syncthreads();
    lo = wrMin(lo); hi = wrMax(hi);
    if((t & 63) == 0){ smem[t >> 6] = lo; smem[4 + (t >> 6)] = hi; }
    __syncthreads();
    if(t == 0){
      ws[W_LOP + b] = fminf(fminf(smem[0],smem[1]),fminf(smem[2],smem[3]));
      ws[W_HIP + b] = fmaxf(fmaxf(smem[4],smem[5]),fmaxf(smem[6],smem[7]));
    }
  }
  gbar(bars, 1);

  // ================= P2: quant + Gram partials + co-max partials =================
  {
    float* Lsh = smem;            // 5120
    float* Rsh = smem + 5120;     // 5120
    const int n = b >> 6, h0 = (b & 63) << 2;
    if(t < 64){
      float lo = ws[W_LOP + n*64 + t];
      float hi = ws[W_HIP + n*64 + t];
      lo = wrMin(lo); hi = wrMax(hi);
      if(t == 0){ smem[10240] = lo; smem[10241] = hi; }
    }
    __syncthreads();
    const float cmin = smem[10240];
    const float dqv  = smem[10241] - cmin;
    float q[16];
#pragma unroll
    for(int l = 0; l < 16; ++l) q[l] = (float)(2*l+1) * (1.0f/32.0f) * dqv + cmin;

    const int m  = t & 15;
    const int g  = t >> 4;
    const int i0 = (m >> 2) << 2;
    const int j0 = (m & 3) << 2;
    float acc[4][4] = {{0.0f}};
    float mp = 0.0f;
    const float* cosp = ws + W_COS + n*65536;

    __syncthreads();
    for(int ch = 0; ch < 4; ++ch){
      const int h = h0 + ch;
      const float cl = cosp[h*256 + t];
      const bool valid = (h < 255) && (t < 255);
      const float cr = valid ? cosp[h*256 + t + 257] : 0.0f;
      float lv[16], rv[16];
      float mL = 0.0f, mR = 0.0f;
#pragma unroll
      for(int l = 0; l < 16; ++l){
        float dl = cl - q[l];
        float Lv = __expf(-32.0f * dl * dl);
        float dr = cr - q[l];
        float Rv = valid ? __expf(-32.0f * dr * dr) : 0.0f;
        lv[l] = Lv; rv[l] = Rv;
        mL = fmaxf(mL, Lv); mR = fmaxf(mR, Rv);
      }
      mp = fmaxf(mp, mL * mR);
      float4* Lp = (float4*)&Lsh[t * 20];
      float4* Rp = (float4*)&Rsh[t * 20];
#pragma unroll
      for(int k = 0; k < 4; ++k){
        Lp[k] = make_float4(lv[4*k], lv[4*k+1], lv[4*k+2], lv[4*k+3]);
        Rp[k] = make_float4(rv[4*k], rv[4*k+1], rv[4*k+2], rv[4*k+3]);
      }
      __syncthreads();
#pragma unroll 4
      for(int it = 0; it < 16; ++it){
        const int p = it * 16 + g;
        const float4 Lx = *(const float4*)&Lsh[p*20 + i0];
        const float4 Rx = *(const float4*)&Rsh[p*20 + j0];
        const float lf[4] = {Lx.x, Lx.y, Lx.z, Lx.w};
        const float rf[4] = {Rx.x, Rx.y, Rx.z, Rx.w};
#pragma unroll
        for(int a = 0; a < 4; ++a)
#pragma unroll
          for(int bb = 0; bb < 4; ++bb) acc[a][bb] += lf[a] * rf[bb];
      }
      __syncthreads();
    }
#pragma unroll
    for(int a = 0; a < 4; ++a)
#pragma unroll
      for(int bb = 0; bb < 4; ++bb)
        Lsh[t*16 + a*4 + bb] = acc[a][bb];
    __syncthreads();
    const int i = t >> 4, j = t & 15;
    const int mm = ((i >> 2) << 2) + (j >> 2);
    const int idx = mm*16 + (i & 3)*4 + (j & 3);
    float v = 0.0f;
#pragma unroll
    for(int gg = 0; gg < 16; ++gg) v += Lsh[gg*256 + idx];
    ws[W_GP + b*256 + t] = v;

    mp = wrMax(mp);
    if((t & 63) == 0) smem[10244 + (t >> 6)] = mp;
    __syncthreads();
    if(t == 0)
      ws[W_CMXP + b] = fmaxf(fmaxf(smem[10244],smem[10245]),fmaxf(smem[10246],smem[10247]));
  }
  gbar(bars, 2);

  // ================= P3: sta + f1(leaky) + f2(relu) -> h2 =================
  {
    for(int k = 0; k < 32; ++k){
      int idx = k*256 + t;
      smem[(idx & 63)*129 + (idx >> 6)] = f2w[idx];    // f2w^T, stride 129
    }
    if(t < 192) smem[8256 + t] = f1w[t];
    if(t < 64)  smem[8448 + t] = f1b[t];
    {
      float m = ws[W_CMXP + t];
      m = wrMax(m);
      if((t & 63) == 0) smem[9536 + (t >> 6)] = m;
    }
    const int n = b >> 6, pos0 = (b & 63) << 2;
    if(t < 64){
      float lo = ws[W_LOP + n*64 + t];
      float hi = ws[W_HIP + n*64 + t];
      lo = wrMin(lo); hi = wrMax(hi);
      if(t == 0){ smem[9540] = lo; smem[9541] = hi; }
    }
    __syncthreads();
    const float comax = fmaxf(fmaxf(smem[9536],smem[9537]),fmaxf(smem[9538],smem[9539]));
    const float cmin = smem[9540];
    const float dqv  = smem[9541] - cmin;
    const int w = t >> 6, j = t & 63;
    const int pos = pos0 + w;
    float gv = ws[W_GP + (n*64 + j)*256 + pos];
    gv = wrSumX(gv);
    const float sta = gv / (comax + 1e-6f);
    const int l1 = pos >> 4, l2 = pos & 15;
    const float ft0 = (float)(2*l2+1)*(1.0f/32.0f)*dqv + cmin;
    const float ft1 = (float)(2*l1+1)*(1.0f/32.0f)*dqv + cmin;
    float a = smem[8256+3*j]*ft0 + smem[8256+3*j+1]*ft1 + smem[8256+3*j+2]*sta + smem[8448+j];
    smem[8512 + w*64 + j] = (a > 0.0f) ? a : 0.01f*a;
    __syncthreads();
    float acc0 = f2b[j], acc1 = f2b[j+64];
    const float* h1p = &smem[8512 + w*64];
#pragma unroll
    for(int c = 0; c < 64; ++c){
      float hv = h1p[c];
      acc0 += smem[c*129 + j]      * hv;
      acc1 += smem[c*129 + j + 64] * hv;
    }
    acc0 = fmaxf(acc0, 0.0f); acc1 = fmaxf(acc1, 0.0f);
    smem[8768 + j*6 + w]        = acc0;
    smem[8768 + (j+64)*6 + w]   = acc1;
    __syncthreads();
    {
      const int ch = t >> 1, hf = t & 1;
      float v0 = smem[8768 + ch*6 + hf*2];
      float v1 = smem[8768 + ch*6 + hf*2 + 1];
      float* dst = ws + W_H2 + n*32768 + ch*256 + pos0 + hf*2;
      dst[0] = v0; dst[1] = v1;
    }
  }
  gbar(bars, 3);

  // ================= P4: o1 conv (raw) + BN1 stats partials =================
  {
    const int ch = b >> 1, hf = b & 1;
    const int n0 = hf * 2;
    if(t < 144) smem[t] = o1w[ch*144 + t];
    if(t >= 192 && t < 224){
      int i = t - 192;               // (n-local)*16 + c
      int nn = n0 + (i >> 4), c = i & 15;
      float s = 0.0f;
      const float* mp = ws + W_MUP + nn*1024 + c;
#pragma unroll 8
      for(int pg = 0; pg < 64; ++pg) s += mp[pg*16];
      smem[144 + i] = s * (1.0f/65536.0f);
    }
    __syncthreads();
    float acc0 = o1b[ch], acc1 = acc0;
#pragma unroll
    for(int c = 0; c < 16; ++c){
      float wv = smem[c];
      acc0 += wv * smem[144 + c];
      acc1 += wv * smem[160 + c];
    }
    const float* h2p = ws + W_H2 + n0*32768 + t;
    for(int c = 0; c < 128; ++c){
      float wv = smem[16 + c];
      acc0 += wv * h2p[c*256];
      acc1 += wv * h2p[32768 + c*256];
    }
    ws[W_RAW + n0*32768     + ch*256 + t] = acc0;
    ws[W_RAW + (n0+1)*32768 + ch*256 + t] = acc1;
    float s = acc0 + acc1, s2 = acc0*acc0 + acc1*acc1;
    s = wrSum(s); s2 = wrSum(s2);
    if((t & 63) == 0){ smem[176 + (t>>6)] = s; smem[180 + (t>>6)] = s2; }
    __syncthreads();
    if(t == 0){
      ws[W_BN1P + (ch*2 + hf)*2]     = smem[176]+smem[177]+smem[178]+smem[179];
      ws[W_BN1P + (ch*2 + hf)*2 + 1] = smem[180]+smem[181]+smem[182]+smem[183];
    }
  }
  gbar(bars, 4);

  // ================= P5: BN1+relu (inline) + o2 conv + BN2 partials =================
  {
    const int ch = b >> 1, hf = b & 1, n0 = hf*2;
    if(t < 128){
      float S  = ws[W_BN1P + (t*2+0)*2]     + ws[W_BN1P + (t*2+1)*2];
      float S2 = ws[W_BN1P + (t*2+0)*2 + 1] + ws[W_BN1P + (t*2+1)*2 + 1];
      float mean = S * (1.0f/1024.0f);
      float var  = S2 * (1.0f/1024.0f) - mean*mean;
      float sc = g1[t] * rsqrtf(var + 1e-5f);
      smem[t]       = sc;
      smem[128 + t] = b1[t] - mean*sc;
      smem[256 + t] = o2w[ch*128 + t];
    }
    __syncthreads();
    float acc0 = o2b[ch], acc1 = acc0;
    const float* rp = ws + W_RAW + n0*32768 + t;
    for(int c = 0; c < 128; ++c){
      float sc = smem[c], sh = smem[128 + c], wv = smem[256 + c];
      float h0v = fmaxf(rp[c*256]*sc + sh, 0.0f);
      float h1v = fmaxf(rp[32768 + c*256]*sc + sh, 0.0f);
      acc0 += wv * h0v; acc1 += wv * h1v;
    }
    float s2 = acc0*acc0 + acc1*acc1;
    float r0 = wrSum(acc0), r1 = wrSum(acc1), r2 = wrSum(s2);
    if((t & 63) == 0){ int w = t>>6; smem[384+w] = r0; smem[388+w] = r1; smem[392+w] = r2; }
    __syncthreads();
    if(t == 0){
      float A0 = smem[384]+smem[385]+smem[386]+smem[387];
      float A1 = smem[388]+smem[389]+smem[390]+smem[391];
      float S2 = smem[392]+smem[393]+smem[394]+smem[395];
      float* dst = ws + W_BN2P + (ch*2 + hf)*4;
      dst[0] = A0; dst[1] = A1; dst[2] = S2;
    }
  }
  gbar(bars, 5);

  // ================= P6: BN2 finalize + threshold/redistribute/normalize =================
  if(b == 0){
    if(t < 128){
      const float* p0 = ws + W_BN2P + (t*2)*4;
      const float* p1 = ws + W_BN2P + (t*2+1)*4;
      float A[4] = {p0[0], p0[1], p1[0], p1[1]};
      float S2 = p0[2] + p1[2];
      float S  = A[0]+A[1]+A[2]+A[3];
      float mean = S * (1.0f/1024.0f);
      float var  = S2 * (1.0f/1024.0f) - mean*mean;
      float sc = g2[t] * rsqrtf(var + 1e-5f);
      float sh = b2[t] - mean*sc;
#pragma unroll
      for(int n = 0; n < 4; ++n) smem[n*128 + t] = A[n]*(1.0f/256.0f)*sc + sh;
    }
    __syncthreads();
    float v0 = smem[t], v1 = smem[256 + t];
    float m = fmaxf(v0, v1);
    m = wrMax(m);
    if((t & 63) == 0) smem[512 + (t>>6)] = m;
    __syncthreads();
    const float mx = fmaxf(fmaxf(smem[512],smem[513]),fmaxf(smem[514],smem[515]));
    const float thr = 0.5f * mx;      // THETA = 0.5
    float e = fmaxf(v0 - thr, 0.0f) + fmaxf(v1 - thr, 0.0f);
    e = wrSum(e);
    if((t & 63) == 0) smem[516 + (t>>6)] = e;
    __syncthreads();
    const float r = (smem[516]+smem[517]+smem[518]+smem[519]) * (1.0f/16.0f);
    const float d0 = (v0 > thr) ? (thr + r) : (v0 + r);
    const float d1 = (v1 > thr) ? (thr + r) : (v1 + r);
    float dn = fminf(d0, d1), dx = fmaxf(d0, d1);
    dn = wrMin(dn); dx = wrMax(dx);
    if((t & 63) == 0){ smem[520 + (t>>6)] = dn; smem[524 + (t>>6)] = dx; }
    __syncthreads();
    const float DN = fminf(fminf(smem[520],smem[521]),fminf(smem[522],smem[523]));
    const float DX = fmaxf(fmaxf(smem[524],smem[525]),fmaxf(smem[526],smem[527]));
    const float inv = 1.0f / (DX - DN + 1e-6f);
    out[t]       = (d0 - DN) * inv;
    out[256 + t] = (d1 - DN) * inv;
  }
}

extern "C" void kernel_launch(void* const* d_in, const int* in_sizes, int n_in,
                              void* d_out, int out_size, void* d_ws, size_t ws_size,
                              hipStream_t stream){
  (void)in_sizes; (void)n_in; (void)out_size; (void)ws_size;
  const float* x   = (const float*)d_in[0];
  const float* f1w = (const float*)d_in[1];
  const float* f1b = (const float*)d_in[2];
  const float* f2w = (const float*)d_in[3];
  const float* f2b = (const float*)d_in[4];
  const float* o1w = (const float*)d_in[5];
  const float* o1b = (const float*)d_in[6];
  const float* g1  = (const float*)d_in[7];
  const float* b1  = (const float*)d_in[8];
  const float* o2w = (const float*)d_in[9];
  const float* o2b = (const float*)d_in[10];
  const float* g2  = (const float*)d_in[11];
  const float* b2  = (const float*)d_in[12];
  float* ws  = (float*)d_ws;
  float* out = (float*)d_out;

  k_zero<<<1, 512, 0, stream>>>(ws);

  void* kargs[] = {
    (void*)&x, (void*)&f1w, (void*)&f1b, (void*)&f2w, (void*)&f2b,
    (void*)&o1w, (void*)&o1b, (void*)&g1, (void*)&b1,
    (void*)&o2w, (void*)&o2b, (void*)&g2, (void*)&b2,
    (void*)&ws, (void*)&out
  };
  hipLaunchCooperativeKernel((void*)k_mega, dim3(NBLK), dim3(256), kargs, 0, stream);
}

// Round 6
// 78.592 us; speedup vs baseline: 2.7005x; 1.5373x over previous
//
#include <hip/hip_runtime.h>
#include <math.h>

// ---------------- ws layout (float indices) ----------------
#define W_MUP   0                       // 256 blocks * 16ch
#define W_LOP   4096                    // 256 cos-min partials
#define W_HIP   4352                    // 256 cos-max partials
#define W_CMXP  4608                    // 256 co-max partials
#define W_DEP   4864                    // 2 departure counters (32-uint spaced)
#define W_BN1F  4992                    // 128 sc + 128 sh
#define W_COS   8192                    // 4*65536
#define W_GP    (W_COS + 262144)        // 256*256 gram partials
#define W_RAW   (W_GP + 65536)          // 4*128*256 o1 pre-BN
#define W_BN1P  (W_RAW + 131072)        // 256 blocks * 256 (S | S2)
#define W_BN2P  (W_BN1P + 65536)        // 256 blocks * 256 (A | S2)

// ---------------- wave-64 reductions ----------------
__device__ __forceinline__ float wrSum(float v){
#pragma unroll
  for(int o = 32; o > 0; o >>= 1) v += __shfl_down(v, o, 64);
  return v;
}
__device__ __forceinline__ float wrSumX(float v){
#pragma unroll
  for(int o = 32; o > 0; o >>= 1) v += __shfl_xor(v, o, 64);
  return v;
}
__device__ __forceinline__ float wrMax(float v){
#pragma unroll
  for(int o = 32; o > 0; o >>= 1) v = fmaxf(v, __shfl_down(v, o, 64));
  return v;
}
__device__ __forceinline__ float wrMin(float v){
#pragma unroll
  for(int o = 32; o > 0; o >>= 1) v = fminf(v, __shfl_down(v, o, 64));
  return v;
}

// ================= K1: mu partials (x pass 1) + zero dep counters =================
__global__ __launch_bounds__(256) void k_mu(const float* __restrict__ x, float* __restrict__ ws){
  __shared__ float red[64];
  const int t = threadIdx.x, b = blockIdx.x;
  const int n = b >> 6, pg = b & 63;
  const float* xb = x + n*1048576 + pg*1024;
  float s[16];
#pragma unroll
  for(int c = 0; c < 16; ++c){
    float4 v = *(const float4*)(xb + c*65536 + t*4);
    s[c] = (v.x+v.y)+(v.z+v.w);
  }
#pragma unroll
  for(int c = 0; c < 16; ++c){
    float r = wrSum(s[c]);
    if((t & 63) == 0) red[c*4 + (t>>6)] = r;
  }
  __syncthreads();
  if(t < 16) ws[W_MUP + b*16 + t] = (red[t*4]+red[t*4+1])+(red[t*4+2]+red[t*4+3]);
  if(b == 0 && t >= 32 && t < 34) ((unsigned*)ws)[W_DEP + (t-32)*32] = 0u;
}

// ================= K2: cos field (x pass 2) + min/max partials =================
__global__ __launch_bounds__(256) void k_cos(const float* __restrict__ x, float* __restrict__ ws){
  __shared__ __align__(16) float smem[1040];
  const int t = threadIdx.x, b = blockIdx.x;
  const int n = b >> 6, rg = b & 63;
  ((float4*)smem)[t] = ((const float4*)(ws + W_MUP + n*1024))[t];
  __syncthreads();
  if(t < 16){
    float s = 0.0f;
#pragma unroll
    for(int pg = 0; pg < 64; ++pg) s += smem[pg*16 + t];
    smem[1024 + t] = s * (1.0f/65536.0f);
  }
  __syncthreads();
  float mn[16], nn = 0.0f;
#pragma unroll
  for(int c = 0; c < 16; ++c){ mn[c] = smem[1024 + c]; nn += mn[c]*mn[c]; }
  const float inv = 1.0f / fmaxf(sqrtf(nn), 1e-12f);
  float lo = 1e30f, hi = -1e30f;
#pragma unroll
  for(int k = 0; k < 4; ++k){
    const int p = (rg*4 + k)*256 + t;
    const float* xp = x + n*1048576 + p;
    float dot = 0.0f, xx = 0.0f;
#pragma unroll
    for(int c = 0; c < 16; ++c){ float v = xp[c*65536]; dot += v*mn[c]; xx += v*v; }
    float cv = dot * inv / fmaxf(sqrtf(xx), 1e-12f);
    ws[W_COS + n*65536 + p] = cv;
    lo = fminf(lo, cv); hi = fmaxf(hi, cv);
  }
  __syncthreads();
  lo = wrMin(lo); hi = wrMax(hi);
  if((t & 63) == 0){ smem[t >> 6] = lo; smem[4 + (t >> 6)] = hi; }
  __syncthreads();
  if(t == 0){
    ws[W_LOP + b] = fminf(fminf(smem[0],smem[1]),fminf(smem[2],smem[3]));
    ws[W_HIP + b] = fmaxf(fmaxf(smem[4],smem[5]),fmaxf(smem[6],smem[7]));
  }
}

// ================= K3: quant + Gram partials + co-max partials =================
__global__ __launch_bounds__(256) void k_gram(float* __restrict__ ws){
  __shared__ __align__(16) float smem[10256];
  float* Lsh = smem;            // 5120
  float* Rsh = smem + 5120;     // 5120
  const int t = threadIdx.x, b = blockIdx.x;
  const int n = b >> 6, h0 = (b & 63) << 2;
  if(t < 64){
    float lo = ws[W_LOP + n*64 + t];
    float hi = ws[W_HIP + n*64 + t];
    lo = wrMin(lo); hi = wrMax(hi);
    if(t == 0){ smem[10240] = lo; smem[10241] = hi; }
  }
  __syncthreads();
  const float cmin = smem[10240];
  const float dqv  = smem[10241] - cmin;
  float q[16];
#pragma unroll
  for(int l = 0; l < 16; ++l) q[l] = (float)(2*l+1) * (1.0f/32.0f) * dqv + cmin;

  const int m  = t & 15;
  const int g  = t >> 4;
  const int i0 = (m >> 2) << 2;
  const int j0 = (m & 3) << 2;
  float acc[4][4] = {{0.0f}};
  float mp = 0.0f;
  const float* cosp = ws + W_COS + n*65536;

  __syncthreads();
  for(int ch = 0; ch < 4; ++ch){
    const int h = h0 + ch;
    const float cl = cosp[h*256 + t];
    const bool valid = (h < 255) && (t < 255);
    const float cr = valid ? cosp[h*256 + t + 257] : 0.0f;
    float lv[16], rv[16];
    float mL = 0.0f, mR = 0.0f;
#pragma unroll
    for(int l = 0; l < 16; ++l){
      float dl = cl - q[l];
      float Lv = __expf(-32.0f * dl * dl);
      float dr = cr - q[l];
      float Rv = valid ? __expf(-32.0f * dr * dr) : 0.0f;
      lv[l] = Lv; rv[l] = Rv;
      mL = fmaxf(mL, Lv); mR = fmaxf(mR, Rv);
    }
    mp = fmaxf(mp, mL * mR);
    float4* Lp = (float4*)&Lsh[t * 20];
    float4* Rp = (float4*)&Rsh[t * 20];
#pragma unroll
    for(int k = 0; k < 4; ++k){
      Lp[k] = make_float4(lv[4*k], lv[4*k+1], lv[4*k+2], lv[4*k+3]);
      Rp[k] = make_float4(rv[4*k], rv[4*k+1], rv[4*k+2], rv[4*k+3]);
    }
    __syncthreads();
#pragma unroll 4
    for(int it = 0; it < 16; ++it){
      const int p = it * 16 + g;
      const float4 Lx = *(const float4*)&Lsh[p*20 + i0];
      const float4 Rx = *(const float4*)&Rsh[p*20 + j0];
      const float lf[4] = {Lx.x, Lx.y, Lx.z, Lx.w};
      const float rf[4] = {Rx.x, Rx.y, Rx.z, Rx.w};
#pragma unroll
      for(int a = 0; a < 4; ++a)
#pragma unroll
        for(int bb = 0; bb < 4; ++bb) acc[a][bb] += lf[a] * rf[bb];
    }
    __syncthreads();
  }
#pragma unroll
  for(int a = 0; a < 4; ++a)
#pragma unroll
    for(int bb = 0; bb < 4; ++bb)
      Lsh[t*16 + a*4 + bb] = acc[a][bb];
  __syncthreads();
  const int i = t >> 4, j = t & 15;
  const int mm = ((i >> 2) << 2) + (j >> 2);
  const int idx = mm*16 + (i & 3)*4 + (j & 3);
  float v = 0.0f;
#pragma unroll
  for(int gg = 0; gg < 16; ++gg) v += Lsh[gg*256 + idx];
  ws[W_GP + b*256 + t] = v;

  mp = wrMax(mp);
  if((t & 63) == 0) smem[10244 + (t >> 6)] = mp;
  __syncthreads();
  if(t == 0)
    ws[W_CMXP + b] = fmaxf(fmaxf(smem[10244],smem[10245]),fmaxf(smem[10246],smem[10247]));
}

// ================= K4: sta + f1 + f2 + o1 conv + BN1 partials (+last-block BN1 finalize) ==========
__global__ __launch_bounds__(256)
void k_mlp1(const float* __restrict__ f1w, const float* __restrict__ f1b,
            const float* __restrict__ f2w, const float* __restrict__ f2b,
            const float* __restrict__ o1w, const float* __restrict__ o1b,
            const float* __restrict__ g1,  const float* __restrict__ b1,
            float* __restrict__ ws)
{
  __shared__ __align__(16) float smem[10496];
  __shared__ unsigned lastFlag;
  const int t = threadIdx.x, b = blockIdx.x;
  const int n = b >> 6, pos0 = (b & 63) << 2;

  // stage f2w^T (stride 129), f1 weights, comax/minmax scalars, xav16
  for(int k = 0; k < 32; ++k){
    int idx = k*256 + t;
    smem[(idx & 63)*129 + (idx >> 6)] = f2w[idx];
  }
  if(t < 192) smem[8256 + t] = f1w[t];
  if(t < 64)  smem[8448 + t] = f1b[t];
  {
    float m2 = ws[W_CMXP + t];
    m2 = wrMax(m2);
    if((t & 63) == 0) smem[9536 + (t >> 6)] = m2;
  }
  if(t < 64){
    float lo = ws[W_LOP + n*64 + t];
    float hi = ws[W_HIP + n*64 + t];
    lo = wrMin(lo); hi = wrMax(hi);
    if(t == 0){ smem[9540] = lo; smem[9541] = hi; }
  }
  if(t >= 64 && t < 80){
    int c = t - 64;
    float s = 0.0f;
    const float* mp = ws + W_MUP + n*1024 + c;
#pragma unroll 8
    for(int pg = 0; pg < 64; ++pg) s += mp[pg*16];
    smem[9552 + c] = s * (1.0f/65536.0f);
  }
  __syncthreads();
  const float comax = fmaxf(fmaxf(smem[9536],smem[9537]),fmaxf(smem[9538],smem[9539]));
  const float cmin = smem[9540];
  const float dqv  = smem[9541] - cmin;
  const int w = t >> 6, j = t & 63;
  const int pos = pos0 + w;
  float gv = ws[W_GP + (n*64 + j)*256 + pos];
  gv = wrSumX(gv);
  const float sta = gv / (comax + 1e-6f);
  const int l1 = pos >> 4, l2 = pos & 15;
  const float ft0 = (float)(2*l2+1)*(1.0f/32.0f)*dqv + cmin;
  const float ft1 = (float)(2*l1+1)*(1.0f/32.0f)*dqv + cmin;
  float a = smem[8256+3*j]*ft0 + smem[8256+3*j+1]*ft1 + smem[8256+3*j+2]*sta + smem[8448+j];
  smem[8512 + w*64 + j] = (a > 0.0f) ? a : 0.01f*a;
  __syncthreads();
  // f2 (relu) -> h2 in smem [ch][w] stride 6
  {
    float acc0 = f2b[j], acc1 = f2b[j+64];
    const float* h1p = &smem[8512 + w*64];
#pragma unroll
    for(int c = 0; c < 64; ++c){
      float hv = h1p[c];
      acc0 += smem[c*129 + j]      * hv;
      acc1 += smem[c*129 + j + 64] * hv;
    }
    acc0 = fmaxf(acc0, 0.0f); acc1 = fmaxf(acc1, 0.0f);
    smem[8768 + j*6 + w]      = acc0;
    smem[8768 + (j+64)*6 + w] = acc1;
  }
  __syncthreads();
  // o1 conv: thread (ch = t&127, w2 = t>>7) computes 2 positions
  {
    const int ch = t & 127, w2 = t >> 7;
    const float* wrow = o1w + ch*144;
    float base = o1b[ch];
#pragma unroll
    for(int c = 0; c < 16; ++c) base += wrow[c] * smem[9552 + c];
#pragma unroll
    for(int k = 0; k < 2; ++k){
      const int ww = w2*2 + k;
      float v = base;
#pragma unroll 8
      for(int c = 0; c < 128; ++c) v += wrow[16 + c] * smem[8768 + c*6 + ww];
      smem[9600 + ch*4 + ww] = v;
    }
  }
  __syncthreads();
  if(t < 128){
    float v0 = smem[9600 + t*4], v1 = smem[9600 + t*4 + 1];
    float v2 = smem[9600 + t*4 + 2], v3 = smem[9600 + t*4 + 3];
    *(float4*)(ws + W_RAW + n*32768 + t*256 + pos0) = make_float4(v0,v1,v2,v3);
    ws[W_BN1P + b*256 + t]       = (v0+v1)+(v2+v3);
    ws[W_BN1P + b*256 + 128 + t] = (v0*v0+v1*v1)+(v2*v2+v3*v3);
  }
  __syncthreads();
  if(t == 0){
    unsigned* dep = (unsigned*)ws + W_DEP;
    lastFlag = __hip_atomic_fetch_add(dep, 1u, __ATOMIC_ACQ_REL, __HIP_MEMORY_SCOPE_AGENT);
  }
  __syncthreads();
  if(lastFlag == 255u){
    // last block: finalize BN1 scale/shift (coalesced column sums)
    float acc2 = 0.0f;
    for(int k = 0; k < 256; ++k) acc2 += ws[W_BN1P + k*256 + t];
    smem[t] = acc2;
    __syncthreads();
    if(t < 128){
      float S = smem[t], S2 = smem[128 + t];
      float mean = S * (1.0f/1024.0f);
      float var  = S2 * (1.0f/1024.0f) - mean*mean;
      float sc = g1[t] * rsqrtf(var + 1e-5f);
      ws[W_BN1F + t]       = sc;
      ws[W_BN1F + 128 + t] = b1[t] - mean*sc;
    }
  }
}

// ================= K5: BN1 apply + o2 conv + BN2 partials (+last-block full epilogue) ============
__global__ __launch_bounds__(256)
void k_mlp2(const float* __restrict__ o2w, const float* __restrict__ o2b,
            const float* __restrict__ g2,  const float* __restrict__ b2,
            float* __restrict__ ws, float* __restrict__ out)
{
  __shared__ __align__(16) float scsh[256];
  __shared__ __align__(16) float h3s[512];
  __shared__ __align__(16) float o2s[512];
  __shared__ __align__(16) float sS[512];
  __shared__ float s2S[128];
  __shared__ float red[16];
  __shared__ unsigned lastFlag;
  const int t = threadIdx.x, b = blockIdx.x;
  const int n = b >> 6, pos0 = (b & 63) << 2;

  scsh[t] = ws[W_BN1F + t];
  __syncthreads();
  if(t < 128){
    float4 rv = *(const float4*)(ws + W_RAW + n*32768 + t*256 + pos0);
    float sc = scsh[t], sh = scsh[128 + t];
    h3s[t*4+0] = fmaxf(rv.x*sc + sh, 0.0f);
    h3s[t*4+1] = fmaxf(rv.y*sc + sh, 0.0f);
    h3s[t*4+2] = fmaxf(rv.z*sc + sh, 0.0f);
    h3s[t*4+3] = fmaxf(rv.w*sc + sh, 0.0f);
  }
  __syncthreads();
  {
    const int ch = t & 127, w2 = t >> 7;
    const float* wrow = o2w + ch*128;
#pragma unroll
    for(int k = 0; k < 2; ++k){
      const int ww = w2*2 + k;
      float v = o2b[ch];
#pragma unroll 8
      for(int c = 0; c < 128; ++c) v += wrow[c] * h3s[c*4 + ww];
      o2s[ch*4 + ww] = v;
    }
  }
  __syncthreads();
  if(t < 128){
    float a0 = o2s[t*4], a1 = o2s[t*4+1], a2 = o2s[t*4+2], a3 = o2s[t*4+3];
    ws[W_BN2P + b*256 + t]       = (a0+a1)+(a2+a3);
    ws[W_BN2P + b*256 + 128 + t] = (a0*a0+a1*a1)+(a2*a2+a3*a3);
  }
  __syncthreads();
  if(t == 0){
    unsigned* dep = (unsigned*)ws + W_DEP + 32;
    lastFlag = __hip_atomic_fetch_add(dep, 1u, __ATOMIC_ACQ_REL, __HIP_MEMORY_SCOPE_AGENT);
  }
  __syncthreads();
  if(lastFlag != 255u) return;

  // ---- last block: BN2 finalize + threshold/redistribute/normalize ----
  if(t < 128){
#pragma unroll
    for(int nn = 0; nn < 4; ++nn){
      float a = 0.0f;
      for(int k = 0; k < 64; ++k) a += ws[W_BN2P + (nn*64 + k)*256 + t];
      sS[nn*128 + t] = a;
    }
  }else{
    const int ch = t - 128;
    float a = 0.0f;
    for(int k = 0; k < 256; ++k) a += ws[W_BN2P + k*256 + 128 + ch];
    s2S[ch] = a;
  }
  __syncthreads();
  if(t < 128){
    float S = ((sS[t] + sS[128+t]) + (sS[256+t] + sS[384+t]));
    float S2 = s2S[t];
    float mean = S * (1.0f/1024.0f);
    float var  = S2 * (1.0f/1024.0f) - mean*mean;
    float sc = g2[t] * rsqrtf(var + 1e-5f);
    float sh = b2[t] - mean*sc;
#pragma unroll
    for(int nn = 0; nn < 4; ++nn)
      sS[nn*128 + t] = sS[nn*128 + t]*(1.0f/256.0f)*sc + sh;
  }
  __syncthreads();
  float v0 = sS[t], v1 = sS[256 + t];
  float m = fmaxf(v0, v1);
  m = wrMax(m);
  if((t & 63) == 0) red[t>>6] = m;
  __syncthreads();
  const float mx = fmaxf(fmaxf(red[0],red[1]),fmaxf(red[2],red[3]));
  const float thr = 0.5f * mx;      // THETA = 0.5
  float e = fmaxf(v0 - thr, 0.0f) + fmaxf(v1 - thr, 0.0f);
  e = wrSum(e);
  if((t & 63) == 0) red[4 + (t>>6)] = e;
  __syncthreads();
  const float r = (red[4]+red[5]+red[6]+red[7]) * (1.0f/16.0f);  // extra / L
  const float d0 = (v0 > thr) ? (thr + r) : (v0 + r);
  const float d1 = (v1 > thr) ? (thr + r) : (v1 + r);
  float dn = fminf(d0, d1), dx = fmaxf(d0, d1);
  dn = wrMin(dn); dx = wrMax(dx);
  if((t & 63) == 0){ red[8 + (t>>6)] = dn; red[12 + (t>>6)] = dx; }
  __syncthreads();
  const float DN = fminf(fminf(red[8],red[9]),fminf(red[10],red[11]));
  const float DX = fmaxf(fmaxf(red[12],red[13]),fmaxf(red[14],red[15]));
  const float inv = 1.0f / (DX - DN + 1e-6f);
  out[t]       = (d0 - DN) * inv;
  out[256 + t] = (d1 - DN) * inv;
}

extern "C" void kernel_launch(void* const* d_in, const int* in_sizes, int n_in,
                              void* d_out, int out_size, void* d_ws, size_t ws_size,
                              hipStream_t stream){
  (void)in_sizes; (void)n_in; (void)out_size; (void)ws_size;
  const float* x   = (const float*)d_in[0];
  const float* f1w = (const float*)d_in[1];
  const float* f1b = (const float*)d_in[2];
  const float* f2w = (const float*)d_in[3];
  const float* f2b = (const float*)d_in[4];
  const float* o1w = (const float*)d_in[5];
  const float* o1b = (const float*)d_in[6];
  const float* g1  = (const float*)d_in[7];
  const float* b1  = (const float*)d_in[8];
  const float* o2w = (const float*)d_in[9];
  const float* o2b = (const float*)d_in[10];
  const float* g2  = (const float*)d_in[11];
  const float* b2  = (const float*)d_in[12];
  float* ws  = (float*)d_ws;
  float* out = (float*)d_out;

  k_mu  <<<256, 256, 0, stream>>>(x, ws);
  k_cos <<<256, 256, 0, stream>>>(x, ws);
  k_gram<<<256, 256, 0, stream>>>(ws);
  k_mlp1<<<256, 256, 0, stream>>>(f1w, f1b, f2w, f2b, o1w, o1b, g1, b1, ws);
  k_mlp2<<<256, 256, 0, stream>>>(o2w, o2b, g2, b2, ws, out);
}